// Round 2
// baseline (1981.036 us; speedup 1.0000x reference)
//
#include <hip/hip_runtime.h>
#include <hip/hip_bf16.h>
#include <math.h>

// Problem constants
#define BB   4
#define SS   1024
#define VV   256
#define KDIM 64
#define HH   8
#define TT   4
#define EPSV 1e-3f
#define SCL  0.125f        // KD^-0.5
#define INV2048 4.8828125e-4f

typedef float f4 __attribute__((ext_vector_type(4)));
typedef short bf8 __attribute__((ext_vector_type(8)));       // 8 bf16
typedef _Float16 h8 __attribute__((ext_vector_type(8)));     // 8 f16
typedef _Float16 h4 __attribute__((ext_vector_type(4)));

#define LDP 68   // fp32 GEMM LDS stride (floats)
#define LHS 68   // split-f16 GEMM LDS stride (halves; 34 dwords -> 2-way, free)

__device__ __forceinline__ short f2bf(float x) {
  __hip_bfloat16 h = __float2bfloat16(x);   // RNE
  return *reinterpret_cast<short*>(&h);
}
__device__ __forceinline__ float bf2f(short h) {
  union { unsigned u; float f; } cv;
  cv.u = ((unsigned)(unsigned short)h) << 16;
  return cv.f;
}

// ---------------------------------------------------------------------------
// fp32 GEMM core (R4, proven) — used only by k_in_dense (1 dispatch).
// ---------------------------------------------------------------------------
__device__ __forceinline__ void gemm_core(
    const float* __restrict__ A, const float* __restrict__ Bm, int ldb,
    float acc[4][4], float (*As)[LDP], float (*Bs)[LDP])
{
  const int tid = threadIdx.x;
  const int tx = tid & 15, ty = tid >> 4;
#pragma unroll
  for (int i = 0; i < 4; i++)
#pragma unroll
    for (int j = 0; j < 4; j++) acc[i][j] = 0.f;

  for (int k0 = 0; k0 < 256; k0 += 16) {
#pragma unroll
    for (int l = 0; l < 4; l++) {
      int e = tid + l * 256;
      int r = e >> 4, kk = e & 15;
      As[kk][r] = A[r * 256 + k0 + kk];
      int rb = e >> 6, nn = e & 63;
      Bs[rb][nn] = Bm[(k0 + rb) * ldb + nn];
    }
    __syncthreads();
#pragma unroll
    for (int kk = 0; kk < 16; kk++) {
      f4 av = *(const f4*)&As[kk][ty * 4];
      f4 bv = *(const f4*)&Bs[kk][tx * 4];
#pragma unroll
      for (int i = 0; i < 4; i++)
#pragma unroll
        for (int j = 0; j < 4; j++)
          acc[i][j] += av[i] * bv[j];
    }
    __syncthreads();
  }
}

// ---------------------------------------------------------------------------
// net0 = x @ W_in, broadcast into all H head slots (R4 verbatim)
// ---------------------------------------------------------------------------
__global__ __launch_bounds__(256) void k_in_dense(
    const float* __restrict__ x, const float* __restrict__ Win,
    float* __restrict__ net)
{
  __shared__ __align__(16) float As[16][LDP];
  __shared__ __align__(16) float Bs[16][LDP];
  const int mt = blockIdx.x, nt = blockIdx.y;
  float acc[4][4];
  gemm_core(x + mt * 64 * 256, Win + nt * 64, 256, acc, As, Bs);
  const int tx = threadIdx.x & 15, ty = threadIdx.x >> 4;
#pragma unroll
  for (int i = 0; i < 4; i++) {
    f4 v;
#pragma unroll
    for (int j = 0; j < 4; j++) v[j] = acc[i][j];
    int row = mt * 64 + ty * 4 + i;
    int col = nt * 64 + tx * 4;
    for (int h = 0; h < HH; h++)
      *(f4*)&net[(size_t)h * 1048576 + row * 256 + col] = v;
  }
}

// ---------------------------------------------------------------------------
// Weight prep (per t): transpose + split into f16 hi/lo, layout [n][k(256)].
// Regions in halves: q: h*16384 ; k: 131072+h*16384 ; v: 262144+h*65536 ;
// d: 786432+h*65536. grid (10, 4 kb, 8 h): x 0=q,1=k,2..5=v,6..9=d.
// ---------------------------------------------------------------------------
__global__ __launch_bounds__(256) void k_prep(
    const float* __restrict__ Wq, const float* __restrict__ Wk,
    const float* __restrict__ Wv, const float* __restrict__ Wd,
    _Float16* __restrict__ oh, _Float16* __restrict__ ol, int t)
{
  __shared__ __align__(16) _Float16 Th[64][LHS];
  __shared__ __align__(16) _Float16 Tl[64][LHS];
  const int xb = blockIdx.x, kb = blockIdx.y, h = blockIdx.z;
  const int tid = threadIdx.x;
  const float* src; int N, nb; size_t dbase;
  if (xb == 0)      { src = Wq; N = 64;  nb = 0;      dbase = (size_t)h * 16384; }
  else if (xb == 1) { src = Wk; N = 64;  nb = 0;      dbase = 131072 + (size_t)h * 16384; }
  else if (xb < 6)  { src = Wv; N = 256; nb = xb - 2; dbase = 262144 + (size_t)h * 65536; }
  else              { src = Wd; N = 256; nb = xb - 6; dbase = 786432 + (size_t)h * 65536; }
  src += (size_t)(h * TT + t) * 256 * N;
  // load 64(k) x 64(n) tile coalesced, split to hi/lo in LDS
#pragma unroll
  for (int i = 0; i < 4; i++) {
    int fi = tid + i * 256;
    int r = fi >> 4, c4 = fi & 15;
    f4 w = *(const f4*)&src[(size_t)(kb * 64 + r) * N + nb * 64 + c4 * 4];
    h4 hv, lv;
#pragma unroll
    for (int j = 0; j < 4; j++) {
      _Float16 hi = (_Float16)w[j];
      hv[j] = hi;
      lv[j] = (_Float16)((w[j] - (float)hi) * 2048.f);
    }
    *(h4*)&Th[r][c4 * 4] = hv;
    *(h4*)&Tl[r][c4 * 4] = lv;
  }
  __syncthreads();
  // write transposed [n][k], coalesced along k
#pragma unroll
  for (int i = 0; i < 4; i++) {
    int fo = tid + i * 256;
    int nr = fo >> 4, k4 = fo & 15;
    h4 hv, lv;
#pragma unroll
    for (int j = 0; j < 4; j++) { hv[j] = Th[k4 * 4 + j][nr]; lv[j] = Tl[k4 * 4 + j][nr]; }
    size_t d = dbase + (size_t)(nb * 64 + nr) * 256 + kb * 64 + k4 * 4;
    *(h4*)&oh[d] = hv;
    *(h4*)&ol[d] = lv;
  }
}

// ---------------------------------------------------------------------------
// Split-f16 MFMA GEMM core: 64x64 tile, K=256 (4 chunks of 64).
// ---------------------------------------------------------------------------
__device__ __forceinline__ void mm_core(
    const float* __restrict__ A,          // tile row 0, lda=256
    const _Float16* __restrict__ Bh,      // n-tile base
    const _Float16* __restrict__ Bl,
    f4 cm[4],
    _Float16 (*Ah)[LHS], _Float16 (*Al)[LHS])
{
  const int tid = threadIdx.x, wv = tid >> 6, lane = tid & 63;
  const int ln = lane & 15, quad = lane >> 4;
  f4 mn[4], cr[4];
#pragma unroll
  for (int mf = 0; mf < 4; mf++) {
    mn[mf] = (f4){0.f, 0.f, 0.f, 0.f};
    cr[mf] = (f4){0.f, 0.f, 0.f, 0.f};
  }
  const _Float16* bhp = Bh + (size_t)(wv * 16 + ln) * 256;
  const _Float16* blp = Bl + (size_t)(wv * 16 + ln) * 256;

  for (int kc = 0; kc < 4; kc++) {
    // stage A chunk 64x64: coalesced f4 loads, split, LDS h4 stores
#pragma unroll
    for (int i = 0; i < 4; i++) {
      int fi = tid + i * 256;
      int r = fi >> 4, c4 = fi & 15;
      f4 w = *(const f4*)&A[(size_t)r * 256 + kc * 64 + c4 * 4];
      h4 hv, lv;
#pragma unroll
      for (int j = 0; j < 4; j++) {
        _Float16 hi = (_Float16)w[j];
        hv[j] = hi;
        lv[j] = (_Float16)((w[j] - (float)hi) * 2048.f);
      }
      *(h4*)&Ah[r][c4 * 4] = hv;
      *(h4*)&Al[r][c4 * 4] = lv;
    }
    // B fragments straight from global (prepped, L2-hot)
    h8 bh0 = *(const h8*)&bhp[kc * 64 + quad * 8];
    h8 bh1 = *(const h8*)&bhp[kc * 64 + 32 + quad * 8];
    h8 bl0 = *(const h8*)&blp[kc * 64 + quad * 8];
    h8 bl1 = *(const h8*)&blp[kc * 64 + 32 + quad * 8];
    __syncthreads();
#pragma unroll
    for (int mf = 0; mf < 4; mf++) {
      h8 ah0 = *(const h8*)&Ah[mf * 16 + ln][quad * 8];
      h8 ah1 = *(const h8*)&Ah[mf * 16 + ln][32 + quad * 8];
      h8 al0 = *(const h8*)&Al[mf * 16 + ln][quad * 8];
      h8 al1 = *(const h8*)&Al[mf * 16 + ln][32 + quad * 8];
      mn[mf] = __builtin_amdgcn_mfma_f32_16x16x32_f16(ah0, bh0, mn[mf], 0, 0, 0);
      mn[mf] = __builtin_amdgcn_mfma_f32_16x16x32_f16(ah1, bh1, mn[mf], 0, 0, 0);
      cr[mf] = __builtin_amdgcn_mfma_f32_16x16x32_f16(ah0, bl0, cr[mf], 0, 0, 0);
      cr[mf] = __builtin_amdgcn_mfma_f32_16x16x32_f16(ah1, bl1, cr[mf], 0, 0, 0);
      cr[mf] = __builtin_amdgcn_mfma_f32_16x16x32_f16(al0, bh0, cr[mf], 0, 0, 0);
      cr[mf] = __builtin_amdgcn_mfma_f32_16x16x32_f16(al1, bh1, cr[mf], 0, 0, 0);
    }
    __syncthreads();
  }
#pragma unroll
  for (int mf = 0; mf < 4; mf++)
#pragma unroll
    for (int r = 0; r < 4; r++)
      cm[mf][r] = mn[mf][r] + cr[mf][r] * INV2048;
}

// ---------------------------------------------------------------------------
// QKV GEMM: q/k -> split-f16 hi/lo in natural [s][kd] layout; v -> bf16 hi/lo
// transposed [h*4+b][vcol][s]. grid (64 mt, 6 nt [0:q 1:k 2..5:v], 8 h)
// ---------------------------------------------------------------------------
__global__ __launch_bounds__(256) void k_mm_qkv(
    const float* __restrict__ net,
    const _Float16* __restrict__ wph, const _Float16* __restrict__ wpl,
    _Float16* __restrict__ qph, _Float16* __restrict__ qpl,
    _Float16* __restrict__ kph, _Float16* __restrict__ kpl,
    short* __restrict__ vth, short* __restrict__ vtl)
{
  __shared__ __align__(16) _Float16 Ah[64][LHS];
  __shared__ __align__(16) _Float16 Al[64][LHS];
  const int mt = blockIdx.x, nt = blockIdx.y, h = blockIdx.z;
  const int tid = threadIdx.x, wv = tid >> 6, lane = tid & 63;
  const int ln = lane & 15, quad = lane >> 4;
  const float* A = net + (size_t)h * 1048576 + (size_t)mt * 64 * 256;
  size_t bbase;
  if (nt == 0)      bbase = (size_t)h * 16384;
  else if (nt == 1) bbase = 131072 + (size_t)h * 16384;
  else              bbase = 262144 + (size_t)h * 65536 + (size_t)(nt - 2) * 64 * 256;
  f4 cm[4];
  mm_core(A, wph + bbase, wpl + bbase, cm, Ah, Al);

  if (nt <= 1) {
    _Float16* dh = (nt == 0) ? qph : kph;
    _Float16* dl = (nt == 0) ? qpl : kpl;
    int col = wv * 16 + ln;
#pragma unroll
    for (int mf = 0; mf < 4; mf++)
#pragma unroll
      for (int r = 0; r < 4; r++) {
        int row = mt * 64 + mf * 16 + quad * 4 + r;
        int b_ = row >> 10, sI = row & 1023;
        float v = cm[mf][r];
        _Float16 hi = (_Float16)v;
        size_t idx = ((size_t)(h * 4 + b_) * 1024 + sI) * 64 + col;
        dh[idx] = hi;
        dl[idx] = (_Float16)((v - (float)hi) * 2048.f);
      }
  } else {
    int c = (nt - 2) * 64 + wv * 16 + ln;
#pragma unroll
    for (int mf = 0; mf < 4; mf++)
#pragma unroll
      for (int r = 0; r < 4; r++) {
        int row = mt * 64 + mf * 16 + quad * 4 + r;
        int b_ = row >> 10, sI = row & 1023;
        float v = cm[mf][r];
        short hi = f2bf(v);
        size_t idx = ((size_t)(h * 4 + b_) * 256 + c) * 1024 + sI;
        vth[idx] = hi;
        vtl[idx] = f2bf(v - bf2f(hi));
      }
  }
}

// ---------------------------------------------------------------------------
// Dense GEMM: tmp = net + relu(net @ Wd). grid (64 mt, 4 nt, 8 h)
// ---------------------------------------------------------------------------
__global__ __launch_bounds__(256) void k_mm_dense(
    const float* __restrict__ net,
    const _Float16* __restrict__ wph, const _Float16* __restrict__ wpl,
    float* __restrict__ tmp)
{
  __shared__ __align__(16) _Float16 Ah[64][LHS];
  __shared__ __align__(16) _Float16 Al[64][LHS];
  const int mt = blockIdx.x, nt = blockIdx.y, h = blockIdx.z;
  const int tid = threadIdx.x, wv = tid >> 6, lane = tid & 63;
  const int ln = lane & 15, quad = lane >> 4;
  const float* A = net + (size_t)h * 1048576 + (size_t)mt * 64 * 256;
  size_t bbase = 786432 + (size_t)h * 65536 + (size_t)nt * 64 * 256;
  f4 cm[4];
  mm_core(A, wph + bbase, wpl + bbase, cm, Ah, Al);

  int col = nt * 64 + wv * 16 + ln;
#pragma unroll
  for (int mf = 0; mf < 4; mf++)
#pragma unroll
    for (int r = 0; r < 4; r++) {
      int row = mt * 64 + mf * 16 + quad * 4 + r;
      size_t idx = (size_t)h * 1048576 + (size_t)row * 256 + col;
      tmp[idx] = net[idx] + fmaxf(cm[mf][r], 0.f);
    }
}

// ---------------------------------------------------------------------------
// Flash attention v3 — K/V direct from global (L1/L2-hot), only P in LDS
// (double-buffered, XOR-swizzled), ONE barrier per K-tile.
// QK^T/softmax: row-band (wave wv owns q-rows wv*16..+16).
// PV: col-band (wave wv owns vcols wv*64..+64); alpha/l broadcast via LDS.
// grid (16 q-tiles, 4 batch, 8 heads)
// ---------------------------------------------------------------------------
__global__ __launch_bounds__(256, 3) void k_attn(
    const _Float16* __restrict__ qfh, const _Float16* __restrict__ qfl,
    const _Float16* __restrict__ kfh, const _Float16* __restrict__ kfl,
    const short* __restrict__ vth, const short* __restrict__ vtl,
    float* __restrict__ ob)
{
  // P[row][col] stored at col ^ ((row&7)<<3): conflict-optimal b128 reads.
  __shared__ __align__(16) short Ph[2][64][64];   // 16 KiB
  __shared__ __align__(16) short Pl[2][64][64];   // 16 KiB
  __shared__ __align__(16) float alS[2][64];      // 512 B
  __shared__ __align__(16) float lrow[64];        // 256 B

  const int qt = blockIdx.x, b = blockIdx.y, h = blockIdx.z;
  const int tid = threadIdx.x;
  const int wv = tid >> 6, lane = tid & 63, ln = lane & 15, quad = lane >> 4;
  const int hb = h * 4 + b;

  // Q fragments: wave wv owns q-rows [qt*64+wv*16, +16). Loaded once.
  const _Float16* qgh = qfh + ((size_t)hb * 1024 + qt * 64 + wv * 16 + ln) * 64;
  const _Float16* qgl = qfl + ((size_t)hb * 1024 + qt * 64 + wv * 16 + ln) * 64;
  h8 aqh0 = *(const h8*)&qgh[quad * 8];
  h8 aqh1 = *(const h8*)&qgh[32 + quad * 8];
  h8 aql0 = *(const h8*)&qgl[quad * 8];
  h8 aql1 = *(const h8*)&qgl[32 + quad * 8];

  const _Float16* kgh = kfh + (size_t)hb * 65536;   // [1024 s][64 kd]
  const _Float16* kgl = kfl + (size_t)hb * 65536;
  // wave's own 64 vcols only (col-band PV — no cross-wave V redundancy)
  const short* vhg = vth + (size_t)hb * 262144 + (size_t)(wv * 64) * 1024;
  const short* vlg = vtl + (size_t)hb * 262144 + (size_t)(wv * 64) * 1024;

  float m[4] = {-1e30f, -1e30f, -1e30f, -1e30f};
  float l[4] = {0.f, 0.f, 0.f, 0.f};
  f4 O[4][4];
#pragma unroll
  for (int mf = 0; mf < 4; mf++)
#pragma unroll
    for (int n2 = 0; n2 < 4; n2++) O[mf][n2] = (f4){0.f, 0.f, 0.f, 0.f};

  const int swz = (ln & 7) << 3;   // read-side XOR (row = mf*16+ln)

  for (int kt = 0; kt < 16; kt++) {
    const int cur = kt & 1;

    // ---- QK^T: K fragments direct from global ----
    f4 sv[4];
#pragma unroll
    for (int nf = 0; nf < 4; nf++) {
      const _Float16* kb  = kgh + (size_t)(kt * 64 + nf * 16 + ln) * 64;
      const _Float16* kbl = kgl + (size_t)(kt * 64 + nf * 16 + ln) * 64;
      h8 bkh0 = *(const h8*)&kb[quad * 8];
      h8 bkh1 = *(const h8*)&kb[32 + quad * 8];
      h8 bkl0 = *(const h8*)&kbl[quad * 8];
      h8 bkl1 = *(const h8*)&kbl[32 + quad * 8];
      f4 mn = (f4){0.f, 0.f, 0.f, 0.f};
      f4 cr = (f4){0.f, 0.f, 0.f, 0.f};
      mn = __builtin_amdgcn_mfma_f32_16x16x32_f16(aqh0, bkh0, mn, 0, 0, 0);
      mn = __builtin_amdgcn_mfma_f32_16x16x32_f16(aqh1, bkh1, mn, 0, 0, 0);
      cr = __builtin_amdgcn_mfma_f32_16x16x32_f16(aqh0, bkl0, cr, 0, 0, 0);
      cr = __builtin_amdgcn_mfma_f32_16x16x32_f16(aqh1, bkl1, cr, 0, 0, 0);
      cr = __builtin_amdgcn_mfma_f32_16x16x32_f16(aql0, bkh0, cr, 0, 0, 0);
      cr = __builtin_amdgcn_mfma_f32_16x16x32_f16(aql1, bkh1, cr, 0, 0, 0);
#pragma unroll
      for (int r = 0; r < 4; r++) sv[nf][r] = (mn[r] + cr[r] * INV2048) * SCL;
    }

    // ---- online softmax (rows wv*16+quad*4+r) ----
    float alpha[4];
#pragma unroll
    for (int r = 0; r < 4; r++) {
      float mloc = fmaxf(fmaxf(sv[0][r], sv[1][r]), fmaxf(sv[2][r], sv[3][r]));
#pragma unroll
      for (int d = 1; d < 16; d <<= 1)
        mloc = fmaxf(mloc, __shfl_xor(mloc, d, 64));
      float mnew = fmaxf(m[r], mloc);
      alpha[r] = __expf(m[r] - mnew);
      float ls = 0.f;
#pragma unroll
      for (int nf = 0; nf < 4; nf++) {
        float p = __expf(sv[nf][r] - mnew);
        sv[nf][r] = p;
        ls += p;
      }
#pragma unroll
      for (int d = 1; d < 16; d <<= 1) ls += __shfl_xor(ls, d, 64);
      l[r] = l[r] * alpha[r] + ls;
      m[r] = mnew;
    }

    // ---- publish alpha + P (own rows) ----
    if (ln == 0) {
      f4 av;
#pragma unroll
      for (int r = 0; r < 4; r++) av[r] = alpha[r];
      *(f4*)&alS[cur][wv * 16 + quad * 4] = av;
    }
#pragma unroll
    for (int nf = 0; nf < 4; nf++)
#pragma unroll
      for (int r = 0; r < 4; r++) {
        int row = wv * 16 + quad * 4 + r;
        int c = (nf * 16 + ln) ^ ((row & 7) << 3);
        float p = sv[nf][r];
        short hi = f2bf(p);
        Ph[cur][row][c] = hi;
        Pl[cur][row][c] = f2bf(p - bf2f(hi));
      }
    __syncthreads();   // the ONLY barrier per kt

    // ---- rescale O by broadcast alpha ----
#pragma unroll
    for (int mf = 0; mf < 4; mf++) {
      f4 av = *(const f4*)&alS[cur][mf * 16 + quad * 4];
#pragma unroll
      for (int n2 = 0; n2 < 4; n2++)
#pragma unroll
        for (int r = 0; r < 4; r++) O[mf][n2][r] *= av[r];
    }

    // ---- PV: V direct from global (own cols), P frags from LDS ----
#pragma unroll
    for (int n2 = 0; n2 < 4; n2++) {
      const short* vb  = vhg + (size_t)(n2 * 16 + ln) * 1024 + kt * 64;
      const short* vbl = vlg + (size_t)(n2 * 16 + ln) * 1024 + kt * 64;
      bf8 vh0 = *(const bf8*)&vb[quad * 8];
      bf8 vh1 = *(const bf8*)&vb[32 + quad * 8];
      bf8 vl0 = *(const bf8*)&vbl[quad * 8];
      bf8 vl1 = *(const bf8*)&vbl[32 + quad * 8];
#pragma unroll
      for (int mf = 0; mf < 4; mf++) {
        bf8 ph0 = *(const bf8*)&Ph[cur][mf * 16 + ln][(quad * 8) ^ swz];
        bf8 ph1 = *(const bf8*)&Ph[cur][mf * 16 + ln][(32 + quad * 8) ^ swz];
        bf8 pl0 = *(const bf8*)&Pl[cur][mf * 16 + ln][(quad * 8) ^ swz];
        bf8 pl1 = *(const bf8*)&Pl[cur][mf * 16 + ln][(32 + quad * 8) ^ swz];
        O[mf][n2] = __builtin_amdgcn_mfma_f32_16x16x32_bf16(ph0, vh0, O[mf][n2], 0, 0, 0);
        O[mf][n2] = __builtin_amdgcn_mfma_f32_16x16x32_bf16(ph1, vh1, O[mf][n2], 0, 0, 0);
        O[mf][n2] = __builtin_amdgcn_mfma_f32_16x16x32_bf16(ph0, vl0, O[mf][n2], 0, 0, 0);
        O[mf][n2] = __builtin_amdgcn_mfma_f32_16x16x32_bf16(ph1, vl1, O[mf][n2], 0, 0, 0);
        O[mf][n2] = __builtin_amdgcn_mfma_f32_16x16x32_bf16(pl0, vh0, O[mf][n2], 0, 0, 0);
        O[mf][n2] = __builtin_amdgcn_mfma_f32_16x16x32_bf16(pl1, vh1, O[mf][n2], 0, 0, 0);
      }
    }
    // no trailing barrier: next iteration writes the OTHER P/alpha buffer
  }

  // ---- epilogue: broadcast 1/l, store (col-band) ----
  if (ln == 0) {
#pragma unroll
    for (int r = 0; r < 4; r++) lrow[wv * 16 + quad * 4 + r] = 1.f / l[r];
  }
  __syncthreads();
#pragma unroll
  for (int mf = 0; mf < 4; mf++) {
    f4 lv = *(const f4*)&lrow[mf * 16 + quad * 4];
#pragma unroll
    for (int r = 0; r < 4; r++) {
      int row = qt * 64 + mf * 16 + quad * 4 + r;
      float* dst = ob + (size_t)h * 1048576 + (size_t)(b * 1024 + row) * 256 + wv * 64;
#pragma unroll
      for (int n2 = 0; n2 < 4; n2++)
        dst[n2 * 16 + ln] = O[mf][n2][r] * lv[r];
    }
  }
}

// ---------------------------------------------------------------------------
// BN stats (R4 verbatim)
// ---------------------------------------------------------------------------
__global__ __launch_bounds__(256) void k_bnstats(
    const float* __restrict__ a, const float* __restrict__ b,
    float* __restrict__ stats, int addB)
{
  const int h = blockIdx.y, r0 = blockIdx.x * 64, c = threadIdx.x;
  const float* pa = a + (size_t)h * 1048576 + r0 * 256 + c;
  float s = 0.f, s2 = 0.f;
  if (addB) {
    const float* pb = b + (size_t)h * 1048576 + r0 * 256 + c;
    for (int r = 0; r < 64; r++) {
      float y = pa[r * 256] + pb[r * 256];
      s += y; s2 += y * y;
    }
  } else {
    for (int r = 0; r < 64; r++) {
      float y = pa[r * 256];
      s += y; s2 += y * y;
    }
  }
  atomicAdd(&stats[(h * 256 + c) * 2], s);
  atomicAdd(&stats[(h * 256 + c) * 2 + 1], s2);
}

// ---------------------------------------------------------------------------
// BN apply (R4 verbatim)
// ---------------------------------------------------------------------------
__global__ __launch_bounds__(256) void k_bnapply(
    const float* __restrict__ a, const float* __restrict__ b,
    const float* __restrict__ stats,
    const float* __restrict__ gamma, const float* __restrict__ beta,
    float* __restrict__ dst, int t, int addB, int transposed)
{
  const int h = blockIdx.y, r0 = blockIdx.x * 64, c = threadIdx.x;
  float s  = stats[(h * 256 + c) * 2];
  float s2 = stats[(h * 256 + c) * 2 + 1];
  float mean = s * (1.f / 4096.f);
  float var  = s2 * (1.f / 4096.f) - mean * mean;
  float inv  = rsqrtf(var + EPSV);
  float g  = gamma[(h * TT + t) * 256 + c] * inv;
  float bt = beta[(h * TT + t) * 256 + c];
  const float* pa = a + (size_t)h * 1048576 + r0 * 256 + c;
  const float* pb = addB ? (b + (size_t)h * 1048576 + r0 * 256 + c) : nullptr;
  for (int r = 0; r < 64; r++) {
    float y = pa[r * 256];
    if (addB) y += pb[r * 256];
    float o = (y - mean) * g + bt;
    int rg = r0 + r;
    if (transposed) dst[((size_t)rg * HH + h) * 256 + c] = o;
    else            dst[(size_t)h * 1048576 + rg * 256 + c] = o;
  }
}

// ---------------------------------------------------------------------------
extern "C" void kernel_launch(void* const* d_in, const int* in_sizes, int n_in,
                              void* d_out, int out_size, void* d_ws, size_t ws_size,
                              hipStream_t stream)
{
  const float* x   = (const float*)d_in[0];
  const float* Win = (const float*)d_in[1];
  const float* Wq  = (const float*)d_in[2];
  const float* Wk  = (const float*)d_in[3];
  const float* Wv  = (const float*)d_in[4];
  const float* Wd  = (const float*)d_in[5];
  const float* g1  = (const float*)d_in[6];
  const float* b1  = (const float*)d_in[7];
  const float* g2  = (const float*)d_in[8];
  const float* b2  = (const float*)d_in[9];
  float* out = (float*)d_out;
  float* ws  = (float*)d_ws;

  float* net   = ws;                       // H*BS*V fp32       =  8,388,608 f
  float* tmp   = net + 8388608;            // H*BS*V fp32       =  8,388,608 f
  float* stats = tmp + 8388608;            // 8 phases * H*V*2  =     32,768 f
  // q/k split-f16 hi/lo, [h*4+b][s][kd] halves
  _Float16* qph = (_Float16*)(stats + 32768);  // 2,097,152 h
  _Float16* qpl = qph + 2097152;               // 2,097,152 h
  _Float16* kph = qpl + 2097152;               // 2,097,152 h
  _Float16* kpl = kph + 2097152;               // 2,097,152 h
  short* vth   = (short*)(kpl + 2097152);  // H*B*V*S bf16 hi   =  8,388,608 s
  short* vtl   = vth + 8388608;            // H*B*V*S bf16 lo   =  8,388,608 s
  _Float16* wph = (_Float16*)(vtl + 8388608);  // prepped weights hi = 1,310,720 h
  _Float16* wpl = wph + 1310720;               // prepped weights lo = 1,310,720 h

  hipMemsetAsync(stats, 0, 8 * HH * VV * 2 * sizeof(float), stream);

  k_in_dense<<<dim3(64, 4), 256, 0, stream>>>(x, Win, net);

  for (int t = 0; t < TT; t++) {
    float* st1 = stats + (t * 2 + 0) * HH * VV * 2;
    float* st2 = stats + (t * 2 + 1) * HH * VV * 2;

    k_prep<<<dim3(10, 4, 8), 256, 0, stream>>>(Wq, Wk, Wv, Wd, wph, wpl, t);
    k_mm_qkv<<<dim3(64, 6, 8), 256, 0, stream>>>(net, wph, wpl, qph, qpl, kph, kpl, vth, vtl);
    k_attn<<<dim3(16, 4, 8), 256, 0, stream>>>(qph, qpl, kph, kpl, vth, vtl, tmp);

    k_bnstats<<<dim3(64, 8), 256, 0, stream>>>(net, tmp, st1, 1);
    k_bnapply<<<dim3(64, 8), 256, 0, stream>>>(net, tmp, st1, g1, b1, net, t, 1, 0);

    k_mm_dense<<<dim3(64, 4, 8), 256, 0, stream>>>(net, wph, wpl, tmp);

    k_bnstats<<<dim3(64, 8), 256, 0, stream>>>(tmp, nullptr, st2, 0);
    if (t < TT - 1)
      k_bnapply<<<dim3(64, 8), 256, 0, stream>>>(tmp, nullptr, st2, g2, b2, net, t, 0, 0);
    else
      k_bnapply<<<dim3(64, 8), 256, 0, stream>>>(tmp, nullptr, st2, g2, b2, out, t, 0, 1);
  }
}

// Round 3
// 1339.902 us; speedup vs baseline: 1.4785x; 1.4785x over previous
//
#include <hip/hip_runtime.h>
#include <hip/hip_bf16.h>
#include <math.h>

// Problem constants
#define BB   4
#define SS   1024
#define VV   256
#define KDIM 64
#define HH   8
#define TT   4
#define EPSV 1e-3f
#define SCL  0.125f        // KD^-0.5
#define INV2048 4.8828125e-4f

typedef float f4 __attribute__((ext_vector_type(4)));
typedef short bf8 __attribute__((ext_vector_type(8)));       // 8 bf16
typedef _Float16 h8 __attribute__((ext_vector_type(8)));     // 8 f16
typedef _Float16 h4 __attribute__((ext_vector_type(4)));

#define LDP 68   // fp32 GEMM LDS stride (floats)
#define LHS 68   // split-f16 GEMM LDS stride (halves; 34 dwords -> 2-way, free)

__device__ __forceinline__ short f2bf(float x) {
  __hip_bfloat16 h = __float2bfloat16(x);   // RNE
  return *reinterpret_cast<short*>(&h);
}
__device__ __forceinline__ float bf2f(short h) {
  union { unsigned u; float f; } cv;
  cv.u = ((unsigned)(unsigned short)h) << 16;
  return cv.f;
}

// ---------------------------------------------------------------------------
// fp32 GEMM core (R4, proven) — used only by k_in_dense (1 dispatch).
// ---------------------------------------------------------------------------
__device__ __forceinline__ void gemm_core(
    const float* __restrict__ A, const float* __restrict__ Bm, int ldb,
    float acc[4][4], float (*As)[LDP], float (*Bs)[LDP])
{
  const int tid = threadIdx.x;
  const int tx = tid & 15, ty = tid >> 4;
#pragma unroll
  for (int i = 0; i < 4; i++)
#pragma unroll
    for (int j = 0; j < 4; j++) acc[i][j] = 0.f;

  for (int k0 = 0; k0 < 256; k0 += 16) {
#pragma unroll
    for (int l = 0; l < 4; l++) {
      int e = tid + l * 256;
      int r = e >> 4, kk = e & 15;
      As[kk][r] = A[r * 256 + k0 + kk];
      int rb = e >> 6, nn = e & 63;
      Bs[rb][nn] = Bm[(k0 + rb) * ldb + nn];
    }
    __syncthreads();
#pragma unroll
    for (int kk = 0; kk < 16; kk++) {
      f4 av = *(const f4*)&As[kk][ty * 4];
      f4 bv = *(const f4*)&Bs[kk][tx * 4];
#pragma unroll
      for (int i = 0; i < 4; i++)
#pragma unroll
        for (int j = 0; j < 4; j++)
          acc[i][j] += av[i] * bv[j];
    }
    __syncthreads();
  }
}

// ---------------------------------------------------------------------------
// net0 = x @ W_in, broadcast into all H head slots (R4 verbatim)
// ---------------------------------------------------------------------------
__global__ __launch_bounds__(256) void k_in_dense(
    const float* __restrict__ x, const float* __restrict__ Win,
    float* __restrict__ net)
{
  __shared__ __align__(16) float As[16][LDP];
  __shared__ __align__(16) float Bs[16][LDP];
  const int mt = blockIdx.x, nt = blockIdx.y;
  float acc[4][4];
  gemm_core(x + mt * 64 * 256, Win + nt * 64, 256, acc, As, Bs);
  const int tx = threadIdx.x & 15, ty = threadIdx.x >> 4;
#pragma unroll
  for (int i = 0; i < 4; i++) {
    f4 v;
#pragma unroll
    for (int j = 0; j < 4; j++) v[j] = acc[i][j];
    int row = mt * 64 + ty * 4 + i;
    int col = nt * 64 + tx * 4;
    for (int h = 0; h < HH; h++)
      *(f4*)&net[(size_t)h * 1048576 + row * 256 + col] = v;
  }
}

// ---------------------------------------------------------------------------
// Weight prep (per t): transpose + split into f16 hi/lo, layout [n][k(256)].
// ---------------------------------------------------------------------------
__global__ __launch_bounds__(256) void k_prep(
    const float* __restrict__ Wq, const float* __restrict__ Wk,
    const float* __restrict__ Wv, const float* __restrict__ Wd,
    _Float16* __restrict__ oh, _Float16* __restrict__ ol, int t)
{
  __shared__ __align__(16) _Float16 Th[64][LHS];
  __shared__ __align__(16) _Float16 Tl[64][LHS];
  const int xb = blockIdx.x, kb = blockIdx.y, h = blockIdx.z;
  const int tid = threadIdx.x;
  const float* src; int N, nb; size_t dbase;
  if (xb == 0)      { src = Wq; N = 64;  nb = 0;      dbase = (size_t)h * 16384; }
  else if (xb == 1) { src = Wk; N = 64;  nb = 0;      dbase = 131072 + (size_t)h * 16384; }
  else if (xb < 6)  { src = Wv; N = 256; nb = xb - 2; dbase = 262144 + (size_t)h * 65536; }
  else              { src = Wd; N = 256; nb = xb - 6; dbase = 786432 + (size_t)h * 65536; }
  src += (size_t)(h * TT + t) * 256 * N;
  // load 64(k) x 64(n) tile coalesced, split to hi/lo in LDS
#pragma unroll
  for (int i = 0; i < 4; i++) {
    int fi = tid + i * 256;
    int r = fi >> 4, c4 = fi & 15;
    f4 w = *(const f4*)&src[(size_t)(kb * 64 + r) * N + nb * 64 + c4 * 4];
    h4 hv, lv;
#pragma unroll
    for (int j = 0; j < 4; j++) {
      _Float16 hi = (_Float16)w[j];
      hv[j] = hi;
      lv[j] = (_Float16)((w[j] - (float)hi) * 2048.f);
    }
    *(h4*)&Th[r][c4 * 4] = hv;
    *(h4*)&Tl[r][c4 * 4] = lv;
  }
  __syncthreads();
  // write transposed [n][k], coalesced along k
#pragma unroll
  for (int i = 0; i < 4; i++) {
    int fo = tid + i * 256;
    int nr = fo >> 4, k4 = fo & 15;
    h4 hv, lv;
#pragma unroll
    for (int j = 0; j < 4; j++) { hv[j] = Th[k4 * 4 + j][nr]; lv[j] = Tl[k4 * 4 + j][nr]; }
    size_t d = dbase + (size_t)(nb * 64 + nr) * 256 + kb * 64 + k4 * 4;
    *(h4*)&oh[d] = hv;
    *(h4*)&ol[d] = lv;
  }
}

// ---------------------------------------------------------------------------
// Split-f16 MFMA GEMM core: 64x64 tile, K=256 (4 chunks of 64).
// ---------------------------------------------------------------------------
__device__ __forceinline__ void mm_core(
    const float* __restrict__ A,          // tile row 0, lda=256
    const _Float16* __restrict__ Bh,      // n-tile base
    const _Float16* __restrict__ Bl,
    f4 cm[4],
    _Float16 (*Ah)[LHS], _Float16 (*Al)[LHS])
{
  const int tid = threadIdx.x, wv = tid >> 6, lane = tid & 63;
  const int ln = lane & 15, quad = lane >> 4;
  f4 mn[4], cr[4];
#pragma unroll
  for (int mf = 0; mf < 4; mf++) {
    mn[mf] = (f4){0.f, 0.f, 0.f, 0.f};
    cr[mf] = (f4){0.f, 0.f, 0.f, 0.f};
  }
  const _Float16* bhp = Bh + (size_t)(wv * 16 + ln) * 256;
  const _Float16* blp = Bl + (size_t)(wv * 16 + ln) * 256;

  for (int kc = 0; kc < 4; kc++) {
    // stage A chunk 64x64: coalesced f4 loads, split, LDS h4 stores
#pragma unroll
    for (int i = 0; i < 4; i++) {
      int fi = tid + i * 256;
      int r = fi >> 4, c4 = fi & 15;
      f4 w = *(const f4*)&A[(size_t)r * 256 + kc * 64 + c4 * 4];
      h4 hv, lv;
#pragma unroll
      for (int j = 0; j < 4; j++) {
        _Float16 hi = (_Float16)w[j];
        hv[j] = hi;
        lv[j] = (_Float16)((w[j] - (float)hi) * 2048.f);
      }
      *(h4*)&Ah[r][c4 * 4] = hv;
      *(h4*)&Al[r][c4 * 4] = lv;
    }
    // B fragments straight from global (prepped, L2-hot)
    h8 bh0 = *(const h8*)&bhp[kc * 64 + quad * 8];
    h8 bh1 = *(const h8*)&bhp[kc * 64 + 32 + quad * 8];
    h8 bl0 = *(const h8*)&blp[kc * 64 + quad * 8];
    h8 bl1 = *(const h8*)&blp[kc * 64 + 32 + quad * 8];
    __syncthreads();
#pragma unroll
    for (int mf = 0; mf < 4; mf++) {
      h8 ah0 = *(const h8*)&Ah[mf * 16 + ln][quad * 8];
      h8 ah1 = *(const h8*)&Ah[mf * 16 + ln][32 + quad * 8];
      h8 al0 = *(const h8*)&Al[mf * 16 + ln][quad * 8];
      h8 al1 = *(const h8*)&Al[mf * 16 + ln][32 + quad * 8];
      mn[mf] = __builtin_amdgcn_mfma_f32_16x16x32_f16(ah0, bh0, mn[mf], 0, 0, 0);
      mn[mf] = __builtin_amdgcn_mfma_f32_16x16x32_f16(ah1, bh1, mn[mf], 0, 0, 0);
      cr[mf] = __builtin_amdgcn_mfma_f32_16x16x32_f16(ah0, bl0, cr[mf], 0, 0, 0);
      cr[mf] = __builtin_amdgcn_mfma_f32_16x16x32_f16(ah1, bl1, cr[mf], 0, 0, 0);
      cr[mf] = __builtin_amdgcn_mfma_f32_16x16x32_f16(al0, bh0, cr[mf], 0, 0, 0);
      cr[mf] = __builtin_amdgcn_mfma_f32_16x16x32_f16(al1, bh1, cr[mf], 0, 0, 0);
    }
    __syncthreads();
  }
#pragma unroll
  for (int mf = 0; mf < 4; mf++)
#pragma unroll
    for (int r = 0; r < 4; r++)
      cm[mf][r] = mn[mf][r] + cr[mf][r] * INV2048;
}

// ---------------------------------------------------------------------------
// QKV GEMM: q/k -> split-f16 hi/lo in natural [s][kd] layout; v -> bf16 hi/lo
// transposed [h*4+b][vcol][s]. grid (64 mt, 6 nt [0:q 1:k 2..5:v], 8 h)
// ---------------------------------------------------------------------------
__global__ __launch_bounds__(256) void k_mm_qkv(
    const float* __restrict__ net,
    const _Float16* __restrict__ wph, const _Float16* __restrict__ wpl,
    _Float16* __restrict__ qph, _Float16* __restrict__ qpl,
    _Float16* __restrict__ kph, _Float16* __restrict__ kpl,
    short* __restrict__ vth, short* __restrict__ vtl)
{
  __shared__ __align__(16) _Float16 Ah[64][LHS];
  __shared__ __align__(16) _Float16 Al[64][LHS];
  const int mt = blockIdx.x, nt = blockIdx.y, h = blockIdx.z;
  const int tid = threadIdx.x, wv = tid >> 6, lane = tid & 63;
  const int ln = lane & 15, quad = lane >> 4;
  const float* A = net + (size_t)h * 1048576 + (size_t)mt * 64 * 256;
  size_t bbase;
  if (nt == 0)      bbase = (size_t)h * 16384;
  else if (nt == 1) bbase = 131072 + (size_t)h * 16384;
  else              bbase = 262144 + (size_t)h * 65536 + (size_t)(nt - 2) * 64 * 256;
  f4 cm[4];
  mm_core(A, wph + bbase, wpl + bbase, cm, Ah, Al);

  if (nt <= 1) {
    _Float16* dh = (nt == 0) ? qph : kph;
    _Float16* dl = (nt == 0) ? qpl : kpl;
    int col = wv * 16 + ln;
#pragma unroll
    for (int mf = 0; mf < 4; mf++)
#pragma unroll
      for (int r = 0; r < 4; r++) {
        int row = mt * 64 + mf * 16 + quad * 4 + r;
        int b_ = row >> 10, sI = row & 1023;
        float v = cm[mf][r];
        _Float16 hi = (_Float16)v;
        size_t idx = ((size_t)(h * 4 + b_) * 1024 + sI) * 64 + col;
        dh[idx] = hi;
        dl[idx] = (_Float16)((v - (float)hi) * 2048.f);
      }
  } else {
    int c = (nt - 2) * 64 + wv * 16 + ln;
#pragma unroll
    for (int mf = 0; mf < 4; mf++)
#pragma unroll
      for (int r = 0; r < 4; r++) {
        int row = mt * 64 + mf * 16 + quad * 4 + r;
        int b_ = row >> 10, sI = row & 1023;
        float v = cm[mf][r];
        short hi = f2bf(v);
        size_t idx = ((size_t)(h * 4 + b_) * 256 + c) * 1024 + sI;
        vth[idx] = hi;
        vtl[idx] = f2bf(v - bf2f(hi));
      }
  }
}

// ---------------------------------------------------------------------------
// Dense GEMM: tmp = net + relu(net @ Wd). grid (64 mt, 4 nt, 8 h)
// ---------------------------------------------------------------------------
__global__ __launch_bounds__(256) void k_mm_dense(
    const float* __restrict__ net,
    const _Float16* __restrict__ wph, const _Float16* __restrict__ wpl,
    float* __restrict__ tmp)
{
  __shared__ __align__(16) _Float16 Ah[64][LHS];
  __shared__ __align__(16) _Float16 Al[64][LHS];
  const int mt = blockIdx.x, nt = blockIdx.y, h = blockIdx.z;
  const int tid = threadIdx.x, wv = tid >> 6, lane = tid & 63;
  const int ln = lane & 15, quad = lane >> 4;
  const float* A = net + (size_t)h * 1048576 + (size_t)mt * 64 * 256;
  size_t bbase = 786432 + (size_t)h * 65536 + (size_t)nt * 64 * 256;
  f4 cm[4];
  mm_core(A, wph + bbase, wpl + bbase, cm, Ah, Al);

  int col = nt * 64 + wv * 16 + ln;
#pragma unroll
  for (int mf = 0; mf < 4; mf++)
#pragma unroll
    for (int r = 0; r < 4; r++) {
      int row = mt * 64 + mf * 16 + quad * 4 + r;
      size_t idx = (size_t)h * 1048576 + (size_t)row * 256 + col;
      tmp[idx] = net[idx] + fmaxf(cm[mf][r], 0.f);
    }
}

// ---------------------------------------------------------------------------
// Flash attention v4 — v2's staged structure, XOR-swizzled unpadded LDS
// (conflict-free, verified pattern from v3's P), double-buffered V with
// register prefetch under MFMA, K prefetched during PV. 5 barriers/K-tile.
// Row-band: wave wv owns q-rows wv*16..+16, all 256 vcols.
// grid (16 q-tiles, 4 batch, 8 heads)
// ---------------------------------------------------------------------------
__global__ __launch_bounds__(256, 2) void k_attn(
    const _Float16* __restrict__ qfh, const _Float16* __restrict__ qfl,
    const _Float16* __restrict__ kfh, const _Float16* __restrict__ kfl,
    const short* __restrict__ vth, const short* __restrict__ vtl,
    float* __restrict__ ob)
{
  // all tiles [64][64] shorts, element col ^= ((row&7)<<3)  (16B-granular)
  __shared__ __align__(16) short KhS[64][64];     // 8 KB (f16 bits)
  __shared__ __align__(16) short KlS[64][64];     // 8 KB
  __shared__ __align__(16) short PhS[64][64];     // 8 KB (bf16 bits)
  __shared__ __align__(16) short PlS[64][64];     // 8 KB
  __shared__ __align__(16) short VhS[2][64][64];  // 16 KB
  __shared__ __align__(16) short VlS[2][64][64];  // 16 KB  => 64 KB total

  const int qt = blockIdx.x, b = blockIdx.y, h = blockIdx.z;
  const int tid = threadIdx.x;
  const int wv = tid >> 6, lane = tid & 63, ln = lane & 15, quad = lane >> 4;
  const int hb = h * 4 + b;
  const int swz = (ln & 7) << 3;    // read-side XOR for rows indexed by ln

  // Q fragments: wave wv owns q-rows [qt*64+wv*16, +16). Loaded once.
  const _Float16* qgh = qfh + ((size_t)hb * 1024 + qt * 64 + wv * 16 + ln) * 64;
  const _Float16* qgl = qfl + ((size_t)hb * 1024 + qt * 64 + wv * 16 + ln) * 64;
  h8 aqh0 = *(const h8*)&qgh[quad * 8];
  h8 aqh1 = *(const h8*)&qgh[32 + quad * 8];
  h8 aql0 = *(const h8*)&qgl[quad * 8];
  h8 aql1 = *(const h8*)&qgl[32 + quad * 8];

  const _Float16* kgh = kfh + (size_t)hb * 65536;   // [1024 s][64 kd]
  const _Float16* kgl = kfl + (size_t)hb * 65536;
  const short* vhg = vth + (size_t)hb * 262144;     // [256 vcol][1024 s]
  const short* vlg = vtl + (size_t)hb * 262144;

  float m[4] = {-1e30f, -1e30f, -1e30f, -1e30f};
  float l[4] = {0.f, 0.f, 0.f, 0.f};
  f4 O[16];
#pragma unroll
  for (int nt = 0; nt < 16; nt++) O[nt] = (f4){0.f, 0.f, 0.f, 0.f};

  // ---- prologue: stage K(0) and V(kt=0, c4=0) into buf 0 ----
#pragma unroll
  for (int i = 0; i < 2; i++) {
    int e = tid + i * 256;
    int r = e >> 3, c8 = e & 7;
    int cc = (c8 * 8) ^ ((r & 7) << 3);
    *(h8*)&KhS[r][cc] = *(const h8*)&kgh[(size_t)r * 64 + c8 * 8];
    *(h8*)&KlS[r][cc] = *(const h8*)&kgl[(size_t)r * 64 + c8 * 8];
  }
#pragma unroll
  for (int i = 0; i < 2; i++) {
    int e = tid + i * 256;
    int vc = e >> 3, fc = e & 7;
    int cc = (fc * 8) ^ ((vc & 7) << 3);
    size_t g = (size_t)vc * 1024 + fc * 8;
    *(bf8*)&VhS[0][vc][cc] = *(const bf8*)&vhg[g];
    *(bf8*)&VlS[0][vc][cc] = *(const bf8*)&vlg[g];
  }
  __syncthreads();   // B0

  for (int kt = 0; kt < 16; kt++) {
    // ---- QK^T: K frags from swizzled LDS ----
    f4 sv[4];
#pragma unroll
    for (int nf = 0; nf < 4; nf++) {
      int row = nf * 16 + ln;
      h8 bkh0 = *(const h8*)&KhS[row][(quad * 8) ^ swz];
      h8 bkh1 = *(const h8*)&KhS[row][(32 + quad * 8) ^ swz];
      h8 bkl0 = *(const h8*)&KlS[row][(quad * 8) ^ swz];
      h8 bkl1 = *(const h8*)&KlS[row][(32 + quad * 8) ^ swz];
      f4 mn = (f4){0.f, 0.f, 0.f, 0.f};
      f4 cr = (f4){0.f, 0.f, 0.f, 0.f};
      mn = __builtin_amdgcn_mfma_f32_16x16x32_f16(aqh0, bkh0, mn, 0, 0, 0);
      mn = __builtin_amdgcn_mfma_f32_16x16x32_f16(aqh1, bkh1, mn, 0, 0, 0);
      cr = __builtin_amdgcn_mfma_f32_16x16x32_f16(aqh0, bkl0, cr, 0, 0, 0);
      cr = __builtin_amdgcn_mfma_f32_16x16x32_f16(aqh1, bkl1, cr, 0, 0, 0);
      cr = __builtin_amdgcn_mfma_f32_16x16x32_f16(aql0, bkh0, cr, 0, 0, 0);
      cr = __builtin_amdgcn_mfma_f32_16x16x32_f16(aql1, bkh1, cr, 0, 0, 0);
#pragma unroll
      for (int r = 0; r < 4; r++) sv[nf][r] = (mn[r] + cr[r] * INV2048) * SCL;
    }

    // ---- online softmax (rows wv*16+quad*4+r) ----
    float alpha[4];
#pragma unroll
    for (int r = 0; r < 4; r++) {
      float mloc = fmaxf(fmaxf(sv[0][r], sv[1][r]), fmaxf(sv[2][r], sv[3][r]));
#pragma unroll
      for (int d = 1; d < 16; d <<= 1)
        mloc = fmaxf(mloc, __shfl_xor(mloc, d, 64));
      float mnew = fmaxf(m[r], mloc);
      alpha[r] = __expf(m[r] - mnew);
      float ls = 0.f;
#pragma unroll
      for (int nf = 0; nf < 4; nf++) {
        float p = __expf(sv[nf][r] - mnew);
        sv[nf][r] = p;
        ls += p;
      }
#pragma unroll
      for (int d = 1; d < 16; d <<= 1) ls += __shfl_xor(ls, d, 64);
      l[r] = l[r] * alpha[r] + ls;
      m[r] = mnew;
    }

    // ---- publish P (swizzled; own rows) ----
#pragma unroll
    for (int nf = 0; nf < 4; nf++)
#pragma unroll
      for (int r = 0; r < 4; r++) {
        int row = wv * 16 + quad * 4 + r;
        int c = (nf * 16 + ln) ^ ((row & 7) << 3);
        float p = sv[nf][r];
        short hi = f2bf(p);
        PhS[row][c] = hi;
        PlS[row][c] = f2bf(p - bf2f(hi));
      }

    // ---- rescale O (own regs) ----
#pragma unroll
    for (int nt = 0; nt < 16; nt++)
#pragma unroll
      for (int i = 0; i < 4; i++) O[nt][i] *= alpha[i];

    __syncthreads();   // B2: P ready (K tile free for overwrite after this phase)

    // ---- P fragments (own 16 rows) ----
    bf8 ph0 = *(const bf8*)&PhS[wv * 16 + ln][(quad * 8) ^ swz];
    bf8 ph1 = *(const bf8*)&PhS[wv * 16 + ln][(32 + quad * 8) ^ swz];
    bf8 pl0 = *(const bf8*)&PlS[wv * 16 + ln][(quad * 8) ^ swz];
    bf8 pl1 = *(const bf8*)&PlS[wv * 16 + ln][(32 + quad * 8) ^ swz];

    // ---- PV over 4 V-chunks, double-buffered with reg prefetch ----
    for (int c4 = 0; c4 < 4; c4++) {
      const int buf = c4 & 1;
      const bool haveNext = (c4 < 3) || (kt < 15);
      const int nkt = (c4 < 3) ? kt : kt + 1;
      const int nc4 = (c4 < 3) ? c4 + 1 : 0;
      const bool pfK = (c4 == 3) && (kt < 15);

      // issue next-chunk global loads (latency hides under MFMAs below)
      const int vc0 = tid >> 3, fc0 = tid & 7;
      const int vc1 = vc0 + 32;
      bf8 fvh0, fvh1, fvl0, fvl1;
      if (haveNext) {
        size_t g0 = (size_t)(nc4 * 64 + vc0) * 1024 + nkt * 64 + fc0 * 8;
        size_t g1 = (size_t)(nc4 * 64 + vc1) * 1024 + nkt * 64 + fc0 * 8;
        fvh0 = *(const bf8*)&vhg[g0]; fvl0 = *(const bf8*)&vlg[g0];
        fvh1 = *(const bf8*)&vhg[g1]; fvl1 = *(const bf8*)&vlg[g1];
      }
      h8 fkh0, fkh1, fkl0, fkl1;
      if (pfK) {
        size_t g0 = (size_t)((kt + 1) * 64 + vc0) * 64 + fc0 * 8;
        size_t g1 = (size_t)((kt + 1) * 64 + vc1) * 64 + fc0 * 8;
        fkh0 = *(const h8*)&kgh[g0]; fkl0 = *(const h8*)&kgl[g0];
        fkh1 = *(const h8*)&kgh[g1]; fkl1 = *(const h8*)&kgl[g1];
      }

      // PV MFMAs on current buffer
#pragma unroll
      for (int n2 = 0; n2 < 4; n2++) {
        int nt = c4 * 4 + n2;
        int vrow = n2 * 16 + ln;
        bf8 vh0 = *(const bf8*)&VhS[buf][vrow][(quad * 8) ^ swz];
        bf8 vh1 = *(const bf8*)&VhS[buf][vrow][(32 + quad * 8) ^ swz];
        bf8 vl0 = *(const bf8*)&VlS[buf][vrow][(quad * 8) ^ swz];
        bf8 vl1 = *(const bf8*)&VlS[buf][vrow][(32 + quad * 8) ^ swz];
        O[nt] = __builtin_amdgcn_mfma_f32_16x16x32_bf16(ph0, vh0, O[nt], 0, 0, 0);
        O[nt] = __builtin_amdgcn_mfma_f32_16x16x32_bf16(ph1, vh1, O[nt], 0, 0, 0);
        O[nt] = __builtin_amdgcn_mfma_f32_16x16x32_bf16(ph0, vl0, O[nt], 0, 0, 0);
        O[nt] = __builtin_amdgcn_mfma_f32_16x16x32_bf16(ph1, vl1, O[nt], 0, 0, 0);
        O[nt] = __builtin_amdgcn_mfma_f32_16x16x32_bf16(pl0, vh0, O[nt], 0, 0, 0);
        O[nt] = __builtin_amdgcn_mfma_f32_16x16x32_bf16(pl1, vh1, O[nt], 0, 0, 0);
      }

      // write prefetched data into the other buffer / K tile
      if (haveNext) {
        int cc0 = (fc0 * 8) ^ ((vc0 & 7) << 3);
        int cc1 = (fc0 * 8) ^ ((vc1 & 7) << 3);
        *(bf8*)&VhS[buf ^ 1][vc0][cc0] = fvh0;
        *(bf8*)&VlS[buf ^ 1][vc0][cc0] = fvl0;
        *(bf8*)&VhS[buf ^ 1][vc1][cc1] = fvh1;
        *(bf8*)&VlS[buf ^ 1][vc1][cc1] = fvl1;
      }
      if (pfK) {
        int cc0 = (fc0 * 8) ^ ((vc0 & 7) << 3);
        int cc1 = (fc0 * 8) ^ ((vc1 & 7) << 3);
        *(h8*)&KhS[vc0][cc0] = fkh0;
        *(h8*)&KlS[vc0][cc0] = fkl0;
        *(h8*)&KhS[vc1][cc1] = fkh1;
        *(h8*)&KlS[vc1][cc1] = fkl1;
      }
      __syncthreads();   // B3[c4]
    }
  }

  // ---- epilogue (own rows/regs; no barrier needed) ----
#pragma unroll
  for (int r = 0; r < 4; r++) {
    float linv = 1.f / l[r];
    int row = qt * 64 + wv * 16 + quad * 4 + r;
    float* dst = ob + (size_t)h * 1048576 + (size_t)(b * 1024 + row) * 256;
#pragma unroll
    for (int nt = 0; nt < 16; nt++)
      dst[nt * 16 + ln] = O[nt][r] * linv;
  }
}

// ---------------------------------------------------------------------------
// BN stats (R4 verbatim)
// ---------------------------------------------------------------------------
__global__ __launch_bounds__(256) void k_bnstats(
    const float* __restrict__ a, const float* __restrict__ b,
    float* __restrict__ stats, int addB)
{
  const int h = blockIdx.y, r0 = blockIdx.x * 64, c = threadIdx.x;
  const float* pa = a + (size_t)h * 1048576 + r0 * 256 + c;
  float s = 0.f, s2 = 0.f;
  if (addB) {
    const float* pb = b + (size_t)h * 1048576 + r0 * 256 + c;
    for (int r = 0; r < 64; r++) {
      float y = pa[r * 256] + pb[r * 256];
      s += y; s2 += y * y;
    }
  } else {
    for (int r = 0; r < 64; r++) {
      float y = pa[r * 256];
      s += y; s2 += y * y;
    }
  }
  atomicAdd(&stats[(h * 256 + c) * 2], s);
  atomicAdd(&stats[(h * 256 + c) * 2 + 1], s2);
}

// ---------------------------------------------------------------------------
// BN apply (R4 verbatim)
// ---------------------------------------------------------------------------
__global__ __launch_bounds__(256) void k_bnapply(
    const float* __restrict__ a, const float* __restrict__ b,
    const float* __restrict__ stats,
    const float* __restrict__ gamma, const float* __restrict__ beta,
    float* __restrict__ dst, int t, int addB, int transposed)
{
  const int h = blockIdx.y, r0 = blockIdx.x * 64, c = threadIdx.x;
  float s  = stats[(h * 256 + c) * 2];
  float s2 = stats[(h * 256 + c) * 2 + 1];
  float mean = s * (1.f / 4096.f);
  float var  = s2 * (1.f / 4096.f) - mean * mean;
  float inv  = rsqrtf(var + EPSV);
  float g  = gamma[(h * TT + t) * 256 + c] * inv;
  float bt = beta[(h * TT + t) * 256 + c];
  const float* pa = a + (size_t)h * 1048576 + r0 * 256 + c;
  const float* pb = addB ? (b + (size_t)h * 1048576 + r0 * 256 + c) : nullptr;
  for (int r = 0; r < 64; r++) {
    float y = pa[r * 256];
    if (addB) y += pb[r * 256];
    float o = (y - mean) * g + bt;
    int rg = r0 + r;
    if (transposed) dst[((size_t)rg * HH + h) * 256 + c] = o;
    else            dst[(size_t)h * 1048576 + rg * 256 + c] = o;
  }
}

// ---------------------------------------------------------------------------
extern "C" void kernel_launch(void* const* d_in, const int* in_sizes, int n_in,
                              void* d_out, int out_size, void* d_ws, size_t ws_size,
                              hipStream_t stream)
{
  const float* x   = (const float*)d_in[0];
  const float* Win = (const float*)d_in[1];
  const float* Wq  = (const float*)d_in[2];
  const float* Wk  = (const float*)d_in[3];
  const float* Wv  = (const float*)d_in[4];
  const float* Wd  = (const float*)d_in[5];
  const float* g1  = (const float*)d_in[6];
  const float* b1  = (const float*)d_in[7];
  const float* g2  = (const float*)d_in[8];
  const float* b2  = (const float*)d_in[9];
  float* out = (float*)d_out;
  float* ws  = (float*)d_ws;

  float* net   = ws;                       // H*BS*V fp32       =  8,388,608 f
  float* tmp   = net + 8388608;            // H*BS*V fp32       =  8,388,608 f
  float* stats = tmp + 8388608;            // 8 phases * H*V*2  =     32,768 f
  // q/k split-f16 hi/lo, [h*4+b][s][kd] halves
  _Float16* qph = (_Float16*)(stats + 32768);  // 2,097,152 h
  _Float16* qpl = qph + 2097152;               // 2,097,152 h
  _Float16* kph = qpl + 2097152;               // 2,097,152 h
  _Float16* kpl = kph + 2097152;               // 2,097,152 h
  short* vth   = (short*)(kpl + 2097152);  // H*B*V*S bf16 hi   =  8,388,608 s
  short* vtl   = vth + 8388608;            // H*B*V*S bf16 lo   =  8,388,608 s
  _Float16* wph = (_Float16*)(vtl + 8388608);  // prepped weights hi = 1,310,720 h
  _Float16* wpl = wph + 1310720;               // prepped weights lo = 1,310,720 h

  hipMemsetAsync(stats, 0, 8 * HH * VV * 2 * sizeof(float), stream);

  k_in_dense<<<dim3(64, 4), 256, 0, stream>>>(x, Win, net);

  for (int t = 0; t < TT; t++) {
    float* st1 = stats + (t * 2 + 0) * HH * VV * 2;
    float* st2 = stats + (t * 2 + 1) * HH * VV * 2;

    k_prep<<<dim3(10, 4, 8), 256, 0, stream>>>(Wq, Wk, Wv, Wd, wph, wpl, t);
    k_mm_qkv<<<dim3(64, 6, 8), 256, 0, stream>>>(net, wph, wpl, qph, qpl, kph, kpl, vth, vtl);
    k_attn<<<dim3(16, 4, 8), 256, 0, stream>>>(qph, qpl, kph, kpl, vth, vtl, tmp);

    k_bnstats<<<dim3(64, 8), 256, 0, stream>>>(net, tmp, st1, 1);
    k_bnapply<<<dim3(64, 8), 256, 0, stream>>>(net, tmp, st1, g1, b1, net, t, 1, 0);

    k_mm_dense<<<dim3(64, 4, 8), 256, 0, stream>>>(net, wph, wpl, tmp);

    k_bnstats<<<dim3(64, 8), 256, 0, stream>>>(tmp, nullptr, st2, 0);
    if (t < TT - 1)
      k_bnapply<<<dim3(64, 8), 256, 0, stream>>>(tmp, nullptr, st2, g2, b2, net, t, 0, 0);
    else
      k_bnapply<<<dim3(64, 8), 256, 0, stream>>>(tmp, nullptr, st2, g2, b2, out, t, 0, 1);
  }
}

// Round 4
// 1060.188 us; speedup vs baseline: 1.8686x; 1.2638x over previous
//
#include <hip/hip_runtime.h>
#include <hip/hip_bf16.h>
#include <math.h>

// Problem constants
#define BB   4
#define SS   1024
#define VV   256
#define KDIM 64
#define HH   8
#define TT   4
#define EPSV 1e-3f
#define SCL  0.125f        // KD^-0.5
#define INV2048 4.8828125e-4f

typedef float f4 __attribute__((ext_vector_type(4)));
typedef short bf8 __attribute__((ext_vector_type(8)));       // 8 bf16
typedef _Float16 h8 __attribute__((ext_vector_type(8)));     // 8 f16
typedef _Float16 h4 __attribute__((ext_vector_type(4)));

#define LDP 68   // fp32 GEMM LDS stride (floats)
#define LHS 68   // split-f16 GEMM LDS stride (halves; 34 dwords -> 2-way, free)

__device__ __forceinline__ short f2bf(float x) {
  __hip_bfloat16 h = __float2bfloat16(x);   // RNE
  return *reinterpret_cast<short*>(&h);
}
__device__ __forceinline__ float bf2f(short h) {
  union { unsigned u; float f; } cv;
  cv.u = ((unsigned)(unsigned short)h) << 16;
  return cv.f;
}

// ---------------------------------------------------------------------------
// fp32 GEMM core (R4, proven) — used only by k_in_dense (1 dispatch).
// ---------------------------------------------------------------------------
__device__ __forceinline__ void gemm_core(
    const float* __restrict__ A, const float* __restrict__ Bm, int ldb,
    float acc[4][4], float (*As)[LDP], float (*Bs)[LDP])
{
  const int tid = threadIdx.x;
  const int tx = tid & 15, ty = tid >> 4;
#pragma unroll
  for (int i = 0; i < 4; i++)
#pragma unroll
    for (int j = 0; j < 4; j++) acc[i][j] = 0.f;

  for (int k0 = 0; k0 < 256; k0 += 16) {
#pragma unroll
    for (int l = 0; l < 4; l++) {
      int e = tid + l * 256;
      int r = e >> 4, kk = e & 15;
      As[kk][r] = A[r * 256 + k0 + kk];
      int rb = e >> 6, nn = e & 63;
      Bs[rb][nn] = Bm[(k0 + rb) * ldb + nn];
    }
    __syncthreads();
#pragma unroll
    for (int kk = 0; kk < 16; kk++) {
      f4 av = *(const f4*)&As[kk][ty * 4];
      f4 bv = *(const f4*)&Bs[kk][tx * 4];
#pragma unroll
      for (int i = 0; i < 4; i++)
#pragma unroll
        for (int j = 0; j < 4; j++)
          acc[i][j] += av[i] * bv[j];
    }
    __syncthreads();
  }
}

// ---------------------------------------------------------------------------
// net0 = x @ W_in, broadcast into all H head slots (R4 verbatim)
// ---------------------------------------------------------------------------
__global__ __launch_bounds__(256) void k_in_dense(
    const float* __restrict__ x, const float* __restrict__ Win,
    float* __restrict__ net)
{
  __shared__ __align__(16) float As[16][LDP];
  __shared__ __align__(16) float Bs[16][LDP];
  const int mt = blockIdx.x, nt = blockIdx.y;
  float acc[4][4];
  gemm_core(x + mt * 64 * 256, Win + nt * 64, 256, acc, As, Bs);
  const int tx = threadIdx.x & 15, ty = threadIdx.x >> 4;
#pragma unroll
  for (int i = 0; i < 4; i++) {
    f4 v;
#pragma unroll
    for (int j = 0; j < 4; j++) v[j] = acc[i][j];
    int row = mt * 64 + ty * 4 + i;
    int col = nt * 64 + tx * 4;
    for (int h = 0; h < HH; h++)
      *(f4*)&net[(size_t)h * 1048576 + row * 256 + col] = v;
  }
}

// ---------------------------------------------------------------------------
// Weight prep (per t): transpose + split into f16 hi/lo, layout [n][k(256)].
// ---------------------------------------------------------------------------
__global__ __launch_bounds__(256) void k_prep(
    const float* __restrict__ Wq, const float* __restrict__ Wk,
    const float* __restrict__ Wv, const float* __restrict__ Wd,
    _Float16* __restrict__ oh, _Float16* __restrict__ ol, int t)
{
  __shared__ __align__(16) _Float16 Th[64][LHS];
  __shared__ __align__(16) _Float16 Tl[64][LHS];
  const int xb = blockIdx.x, kb = blockIdx.y, h = blockIdx.z;
  const int tid = threadIdx.x;
  const float* src; int N, nb; size_t dbase;
  if (xb == 0)      { src = Wq; N = 64;  nb = 0;      dbase = (size_t)h * 16384; }
  else if (xb == 1) { src = Wk; N = 64;  nb = 0;      dbase = 131072 + (size_t)h * 16384; }
  else if (xb < 6)  { src = Wv; N = 256; nb = xb - 2; dbase = 262144 + (size_t)h * 65536; }
  else              { src = Wd; N = 256; nb = xb - 6; dbase = 786432 + (size_t)h * 65536; }
  src += (size_t)(h * TT + t) * 256 * N;
  // load 64(k) x 64(n) tile coalesced, split to hi/lo in LDS
#pragma unroll
  for (int i = 0; i < 4; i++) {
    int fi = tid + i * 256;
    int r = fi >> 4, c4 = fi & 15;
    f4 w = *(const f4*)&src[(size_t)(kb * 64 + r) * N + nb * 64 + c4 * 4];
    h4 hv, lv;
#pragma unroll
    for (int j = 0; j < 4; j++) {
      _Float16 hi = (_Float16)w[j];
      hv[j] = hi;
      lv[j] = (_Float16)((w[j] - (float)hi) * 2048.f);
    }
    *(h4*)&Th[r][c4 * 4] = hv;
    *(h4*)&Tl[r][c4 * 4] = lv;
  }
  __syncthreads();
  // write transposed [n][k], coalesced along k
#pragma unroll
  for (int i = 0; i < 4; i++) {
    int fo = tid + i * 256;
    int nr = fo >> 4, k4 = fo & 15;
    h4 hv, lv;
#pragma unroll
    for (int j = 0; j < 4; j++) { hv[j] = Th[k4 * 4 + j][nr]; lv[j] = Tl[k4 * 4 + j][nr]; }
    size_t d = dbase + (size_t)(nb * 64 + nr) * 256 + kb * 64 + k4 * 4;
    *(h4*)&oh[d] = hv;
    *(h4*)&ol[d] = lv;
  }
}

// ---------------------------------------------------------------------------
// A-tile staging helpers for merged GEMMs: issue global loads to regs,
// split+write to LDS later (latency hides under MFMAs).
// ---------------------------------------------------------------------------
__device__ __forceinline__ void stage_issue(
    const float* __restrict__ A, int kc, int tid, f4 w[4])
{
#pragma unroll
  for (int i = 0; i < 4; i++) {
    int fi = tid + i * 256;
    int r = fi >> 4, c4 = fi & 15;
    w[i] = *(const f4*)&A[(size_t)r * 256 + kc * 64 + c4 * 4];
  }
}
__device__ __forceinline__ void stage_write(
    const f4 w[4], int tid, _Float16 (*Ah)[LHS], _Float16 (*Al)[LHS])
{
#pragma unroll
  for (int i = 0; i < 4; i++) {
    int fi = tid + i * 256;
    int r = fi >> 4, c4 = fi & 15;
    h4 hv, lv;
#pragma unroll
    for (int j = 0; j < 4; j++) {
      _Float16 hi = (_Float16)w[i][j];
      hv[j] = hi;
      lv[j] = (_Float16)((w[i][j] - (float)hi) * 2048.f);
    }
    *(h4*)&Ah[r][c4 * 4] = hv;
    *(h4*)&Al[r][c4 * 4] = lv;
  }
}

// ---------------------------------------------------------------------------
// QKV GEMM (merged): one block per (mt, h) computes ALL 6 col-groups
// (q, k, v0..v3), in 2 halves of 3 to bound acc registers. A staged once
// per half, double-buffered across kc, prefetched under MFMAs.
// 1 barrier per kc. grid (64 mt, 8 h).
// ---------------------------------------------------------------------------
__global__ __launch_bounds__(256) void k_mm_qkv(
    const float* __restrict__ net,
    const _Float16* __restrict__ wph, const _Float16* __restrict__ wpl,
    _Float16* __restrict__ qph, _Float16* __restrict__ qpl,
    _Float16* __restrict__ kph, _Float16* __restrict__ kpl,
    short* __restrict__ vth, short* __restrict__ vtl)
{
  __shared__ __align__(16) _Float16 Ah[2][64][LHS];
  __shared__ __align__(16) _Float16 Al[2][64][LHS];
  const int mt = blockIdx.x, h = blockIdx.y;
  const int tid = threadIdx.x, wv = tid >> 6, lane = tid & 63;
  const int ln = lane & 15, quad = lane >> 4;
  const float* A = net + (size_t)h * 1048576 + (size_t)mt * 64 * 256;

  for (int half = 0; half < 2; half++) {
    // wave-uniform B bases for the 3 col-groups of this half
    size_t bb[3];
#pragma unroll
    for (int j = 0; j < 3; j++) {
      int nt = half * 3 + j;
      if (nt == 0)      bb[j] = (size_t)h * 16384;
      else if (nt == 1) bb[j] = 131072 + (size_t)h * 16384;
      else              bb[j] = 262144 + (size_t)h * 65536 + (size_t)(nt - 2) * 16384;
      bb[j] += (size_t)(wv * 16 + ln) * 256;
    }

    f4 mn[3][4], cr[3][4];
#pragma unroll
    for (int j = 0; j < 3; j++)
#pragma unroll
      for (int mf = 0; mf < 4; mf++) {
        mn[j][mf] = (f4){0.f, 0.f, 0.f, 0.f};
        cr[j][mf] = (f4){0.f, 0.f, 0.f, 0.f};
      }

    // prologue: stage kc=0 into buf 0
    f4 w[4];
    stage_issue(A, 0, tid, w);
    stage_write(w, tid, Ah[0], Al[0]);
    __syncthreads();

    for (int kc = 0; kc < 4; kc++) {
      const int buf = kc & 1;
      if (kc < 3) stage_issue(A, kc + 1, tid, w);   // prefetch under MFMAs
#pragma unroll
      for (int j = 0; j < 3; j++) {
        const _Float16* bh = wph + bb[j] + kc * 64;
        const _Float16* bl = wpl + bb[j] + kc * 64;
        h8 bh0 = *(const h8*)&bh[quad * 8];
        h8 bh1 = *(const h8*)&bh[32 + quad * 8];
        h8 bl0 = *(const h8*)&bl[quad * 8];
        h8 bl1 = *(const h8*)&bl[32 + quad * 8];
#pragma unroll
        for (int mf = 0; mf < 4; mf++) {
          h8 ah0 = *(const h8*)&Ah[buf][mf * 16 + ln][quad * 8];
          h8 ah1 = *(const h8*)&Ah[buf][mf * 16 + ln][32 + quad * 8];
          h8 al0 = *(const h8*)&Al[buf][mf * 16 + ln][quad * 8];
          h8 al1 = *(const h8*)&Al[buf][mf * 16 + ln][32 + quad * 8];
          mn[j][mf] = __builtin_amdgcn_mfma_f32_16x16x32_f16(ah0, bh0, mn[j][mf], 0, 0, 0);
          mn[j][mf] = __builtin_amdgcn_mfma_f32_16x16x32_f16(ah1, bh1, mn[j][mf], 0, 0, 0);
          cr[j][mf] = __builtin_amdgcn_mfma_f32_16x16x32_f16(ah0, bl0, cr[j][mf], 0, 0, 0);
          cr[j][mf] = __builtin_amdgcn_mfma_f32_16x16x32_f16(ah1, bl1, cr[j][mf], 0, 0, 0);
          cr[j][mf] = __builtin_amdgcn_mfma_f32_16x16x32_f16(al0, bh0, cr[j][mf], 0, 0, 0);
          cr[j][mf] = __builtin_amdgcn_mfma_f32_16x16x32_f16(al1, bh1, cr[j][mf], 0, 0, 0);
        }
      }
      if (kc < 3) stage_write(w, tid, Ah[buf ^ 1], Al[buf ^ 1]);
      __syncthreads();
    }

    // epilogue for this half
#pragma unroll
    for (int j = 0; j < 3; j++) {
      int nt = half * 3 + j;
      if (nt <= 1) {
        _Float16* dh = (nt == 0) ? qph : kph;
        _Float16* dl = (nt == 0) ? qpl : kpl;
        int col = wv * 16 + ln;
#pragma unroll
        for (int mf = 0; mf < 4; mf++)
#pragma unroll
          for (int r = 0; r < 4; r++) {
            int row = mt * 64 + mf * 16 + quad * 4 + r;
            int b_ = row >> 10, sI = row & 1023;
            float v = mn[j][mf][r] + cr[j][mf][r] * INV2048;
            _Float16 hi = (_Float16)v;
            size_t idx = ((size_t)(h * 4 + b_) * 1024 + sI) * 64 + col;
            dh[idx] = hi;
            dl[idx] = (_Float16)((v - (float)hi) * 2048.f);
          }
      } else {
        int c = (nt - 2) * 64 + wv * 16 + ln;
#pragma unroll
        for (int mf = 0; mf < 4; mf++)
#pragma unroll
          for (int r = 0; r < 4; r++) {
            int row = mt * 64 + mf * 16 + quad * 4 + r;
            int b_ = row >> 10, sI = row & 1023;
            float v = mn[j][mf][r] + cr[j][mf][r] * INV2048;
            short hi = f2bf(v);
            size_t idx = ((size_t)(h * 4 + b_) * 256 + c) * 1024 + sI;
            vth[idx] = hi;
            vtl[idx] = f2bf(v - bf2f(hi));
          }
      }
    }
  }
}

// ---------------------------------------------------------------------------
// Dense GEMM (merged): tmp = net + relu(net @ Wd). One block per (mt, h),
// all 4 col-groups in 2 halves of 2. grid (64 mt, 8 h).
// ---------------------------------------------------------------------------
__global__ __launch_bounds__(256) void k_mm_dense(
    const float* __restrict__ net,
    const _Float16* __restrict__ wph, const _Float16* __restrict__ wpl,
    float* __restrict__ tmp)
{
  __shared__ __align__(16) _Float16 Ah[2][64][LHS];
  __shared__ __align__(16) _Float16 Al[2][64][LHS];
  const int mt = blockIdx.x, h = blockIdx.y;
  const int tid = threadIdx.x, wv = tid >> 6, lane = tid & 63;
  const int ln = lane & 15, quad = lane >> 4;
  const float* A = net + (size_t)h * 1048576 + (size_t)mt * 64 * 256;

  for (int half = 0; half < 2; half++) {
    size_t bb[2];
#pragma unroll
    for (int j = 0; j < 2; j++) {
      int nt = half * 2 + j;
      bb[j] = 786432 + (size_t)h * 65536 + (size_t)nt * 16384
            + (size_t)(wv * 16 + ln) * 256;
    }

    f4 mn[2][4], cr[2][4];
#pragma unroll
    for (int j = 0; j < 2; j++)
#pragma unroll
      for (int mf = 0; mf < 4; mf++) {
        mn[j][mf] = (f4){0.f, 0.f, 0.f, 0.f};
        cr[j][mf] = (f4){0.f, 0.f, 0.f, 0.f};
      }

    f4 w[4];
    stage_issue(A, 0, tid, w);
    stage_write(w, tid, Ah[0], Al[0]);
    __syncthreads();

    for (int kc = 0; kc < 4; kc++) {
      const int buf = kc & 1;
      if (kc < 3) stage_issue(A, kc + 1, tid, w);
#pragma unroll
      for (int j = 0; j < 2; j++) {
        const _Float16* bh = wph + bb[j] + kc * 64;
        const _Float16* bl = wpl + bb[j] + kc * 64;
        h8 bh0 = *(const h8*)&bh[quad * 8];
        h8 bh1 = *(const h8*)&bh[32 + quad * 8];
        h8 bl0 = *(const h8*)&bl[quad * 8];
        h8 bl1 = *(const h8*)&bl[32 + quad * 8];
#pragma unroll
        for (int mf = 0; mf < 4; mf++) {
          h8 ah0 = *(const h8*)&Ah[buf][mf * 16 + ln][quad * 8];
          h8 ah1 = *(const h8*)&Ah[buf][mf * 16 + ln][32 + quad * 8];
          h8 al0 = *(const h8*)&Al[buf][mf * 16 + ln][quad * 8];
          h8 al1 = *(const h8*)&Al[buf][mf * 16 + ln][32 + quad * 8];
          mn[j][mf] = __builtin_amdgcn_mfma_f32_16x16x32_f16(ah0, bh0, mn[j][mf], 0, 0, 0);
          mn[j][mf] = __builtin_amdgcn_mfma_f32_16x16x32_f16(ah1, bh1, mn[j][mf], 0, 0, 0);
          cr[j][mf] = __builtin_amdgcn_mfma_f32_16x16x32_f16(ah0, bl0, cr[j][mf], 0, 0, 0);
          cr[j][mf] = __builtin_amdgcn_mfma_f32_16x16x32_f16(ah1, bl1, cr[j][mf], 0, 0, 0);
          cr[j][mf] = __builtin_amdgcn_mfma_f32_16x16x32_f16(al0, bh0, cr[j][mf], 0, 0, 0);
          cr[j][mf] = __builtin_amdgcn_mfma_f32_16x16x32_f16(al1, bh1, cr[j][mf], 0, 0, 0);
        }
      }
      if (kc < 3) stage_write(w, tid, Ah[buf ^ 1], Al[buf ^ 1]);
      __syncthreads();
    }

#pragma unroll
    for (int j = 0; j < 2; j++) {
      int nt = half * 2 + j;
      int col = nt * 64 + wv * 16 + ln;
#pragma unroll
      for (int mf = 0; mf < 4; mf++)
#pragma unroll
        for (int r = 0; r < 4; r++) {
          int row = mt * 64 + mf * 16 + quad * 4 + r;
          size_t idx = (size_t)h * 1048576 + (size_t)row * 256 + col;
          float v = mn[j][mf][r] + cr[j][mf][r] * INV2048;
          tmp[idx] = net[idx] + fmaxf(v, 0.f);
        }
    }
  }
}

// ---------------------------------------------------------------------------
// Flash attention v4 (verbatim from previous round — proven).
// ---------------------------------------------------------------------------
__global__ __launch_bounds__(256, 2) void k_attn(
    const _Float16* __restrict__ qfh, const _Float16* __restrict__ qfl,
    const _Float16* __restrict__ kfh, const _Float16* __restrict__ kfl,
    const short* __restrict__ vth, const short* __restrict__ vtl,
    float* __restrict__ ob)
{
  // all tiles [64][64] shorts, element col ^= ((row&7)<<3)  (16B-granular)
  __shared__ __align__(16) short KhS[64][64];     // 8 KB (f16 bits)
  __shared__ __align__(16) short KlS[64][64];     // 8 KB
  __shared__ __align__(16) short PhS[64][64];     // 8 KB (bf16 bits)
  __shared__ __align__(16) short PlS[64][64];     // 8 KB
  __shared__ __align__(16) short VhS[2][64][64];  // 16 KB
  __shared__ __align__(16) short VlS[2][64][64];  // 16 KB  => 64 KB total

  const int qt = blockIdx.x, b = blockIdx.y, h = blockIdx.z;
  const int tid = threadIdx.x;
  const int wv = tid >> 6, lane = tid & 63, ln = lane & 15, quad = lane >> 4;
  const int hb = h * 4 + b;
  const int swz = (ln & 7) << 3;    // read-side XOR for rows indexed by ln

  // Q fragments: wave wv owns q-rows [qt*64+wv*16, +16). Loaded once.
  const _Float16* qgh = qfh + ((size_t)hb * 1024 + qt * 64 + wv * 16 + ln) * 64;
  const _Float16* qgl = qfl + ((size_t)hb * 1024 + qt * 64 + wv * 16 + ln) * 64;
  h8 aqh0 = *(const h8*)&qgh[quad * 8];
  h8 aqh1 = *(const h8*)&qgh[32 + quad * 8];
  h8 aql0 = *(const h8*)&qgl[quad * 8];
  h8 aql1 = *(const h8*)&qgl[32 + quad * 8];

  const _Float16* kgh = kfh + (size_t)hb * 65536;   // [1024 s][64 kd]
  const _Float16* kgl = kfl + (size_t)hb * 65536;
  const short* vhg = vth + (size_t)hb * 262144;     // [256 vcol][1024 s]
  const short* vlg = vtl + (size_t)hb * 262144;

  float m[4] = {-1e30f, -1e30f, -1e30f, -1e30f};
  float l[4] = {0.f, 0.f, 0.f, 0.f};
  f4 O[16];
#pragma unroll
  for (int nt = 0; nt < 16; nt++) O[nt] = (f4){0.f, 0.f, 0.f, 0.f};

  // ---- prologue: stage K(0) and V(kt=0, c4=0) into buf 0 ----
#pragma unroll
  for (int i = 0; i < 2; i++) {
    int e = tid + i * 256;
    int r = e >> 3, c8 = e & 7;
    int cc = (c8 * 8) ^ ((r & 7) << 3);
    *(h8*)&KhS[r][cc] = *(const h8*)&kgh[(size_t)r * 64 + c8 * 8];
    *(h8*)&KlS[r][cc] = *(const h8*)&kgl[(size_t)r * 64 + c8 * 8];
  }
#pragma unroll
  for (int i = 0; i < 2; i++) {
    int e = tid + i * 256;
    int vc = e >> 3, fc = e & 7;
    int cc = (fc * 8) ^ ((vc & 7) << 3);
    size_t g = (size_t)vc * 1024 + fc * 8;
    *(bf8*)&VhS[0][vc][cc] = *(const bf8*)&vhg[g];
    *(bf8*)&VlS[0][vc][cc] = *(const bf8*)&vlg[g];
  }
  __syncthreads();   // B0

  for (int kt = 0; kt < 16; kt++) {
    // ---- QK^T: K frags from swizzled LDS ----
    f4 sv[4];
#pragma unroll
    for (int nf = 0; nf < 4; nf++) {
      int row = nf * 16 + ln;
      h8 bkh0 = *(const h8*)&KhS[row][(quad * 8) ^ swz];
      h8 bkh1 = *(const h8*)&KhS[row][(32 + quad * 8) ^ swz];
      h8 bkl0 = *(const h8*)&KlS[row][(quad * 8) ^ swz];
      h8 bkl1 = *(const h8*)&KlS[row][(32 + quad * 8) ^ swz];
      f4 mn = (f4){0.f, 0.f, 0.f, 0.f};
      f4 cr = (f4){0.f, 0.f, 0.f, 0.f};
      mn = __builtin_amdgcn_mfma_f32_16x16x32_f16(aqh0, bkh0, mn, 0, 0, 0);
      mn = __builtin_amdgcn_mfma_f32_16x16x32_f16(aqh1, bkh1, mn, 0, 0, 0);
      cr = __builtin_amdgcn_mfma_f32_16x16x32_f16(aqh0, bkl0, cr, 0, 0, 0);
      cr = __builtin_amdgcn_mfma_f32_16x16x32_f16(aqh1, bkl1, cr, 0, 0, 0);
      cr = __builtin_amdgcn_mfma_f32_16x16x32_f16(aql0, bkh0, cr, 0, 0, 0);
      cr = __builtin_amdgcn_mfma_f32_16x16x32_f16(aql1, bkh1, cr, 0, 0, 0);
#pragma unroll
      for (int r = 0; r < 4; r++) sv[nf][r] = (mn[r] + cr[r] * INV2048) * SCL;
    }

    // ---- online softmax (rows wv*16+quad*4+r) ----
    float alpha[4];
#pragma unroll
    for (int r = 0; r < 4; r++) {
      float mloc = fmaxf(fmaxf(sv[0][r], sv[1][r]), fmaxf(sv[2][r], sv[3][r]));
#pragma unroll
      for (int d = 1; d < 16; d <<= 1)
        mloc = fmaxf(mloc, __shfl_xor(mloc, d, 64));
      float mnew = fmaxf(m[r], mloc);
      alpha[r] = __expf(m[r] - mnew);
      float ls = 0.f;
#pragma unroll
      for (int nf = 0; nf < 4; nf++) {
        float p = __expf(sv[nf][r] - mnew);
        sv[nf][r] = p;
        ls += p;
      }
#pragma unroll
      for (int d = 1; d < 16; d <<= 1) ls += __shfl_xor(ls, d, 64);
      l[r] = l[r] * alpha[r] + ls;
      m[r] = mnew;
    }

    // ---- publish P (swizzled; own rows) ----
#pragma unroll
    for (int nf = 0; nf < 4; nf++)
#pragma unroll
      for (int r = 0; r < 4; r++) {
        int row = wv * 16 + quad * 4 + r;
        int c = (nf * 16 + ln) ^ ((row & 7) << 3);
        float p = sv[nf][r];
        short hi = f2bf(p);
        PhS[row][c] = hi;
        PlS[row][c] = f2bf(p - bf2f(hi));
      }

    // ---- rescale O (own regs) ----
#pragma unroll
    for (int nt = 0; nt < 16; nt++)
#pragma unroll
      for (int i = 0; i < 4; i++) O[nt][i] *= alpha[i];

    __syncthreads();   // B2: P ready (K tile free for overwrite after this phase)

    // ---- P fragments (own 16 rows) ----
    bf8 ph0 = *(const bf8*)&PhS[wv * 16 + ln][(quad * 8) ^ swz];
    bf8 ph1 = *(const bf8*)&PhS[wv * 16 + ln][(32 + quad * 8) ^ swz];
    bf8 pl0 = *(const bf8*)&PlS[wv * 16 + ln][(quad * 8) ^ swz];
    bf8 pl1 = *(const bf8*)&PlS[wv * 16 + ln][(32 + quad * 8) ^ swz];

    // ---- PV over 4 V-chunks, double-buffered with reg prefetch ----
    for (int c4 = 0; c4 < 4; c4++) {
      const int buf = c4 & 1;
      const bool haveNext = (c4 < 3) || (kt < 15);
      const int nkt = (c4 < 3) ? kt : kt + 1;
      const int nc4 = (c4 < 3) ? c4 + 1 : 0;
      const bool pfK = (c4 == 3) && (kt < 15);

      // issue next-chunk global loads (latency hides under MFMAs below)
      const int vc0 = tid >> 3, fc0 = tid & 7;
      const int vc1 = vc0 + 32;
      bf8 fvh0, fvh1, fvl0, fvl1;
      if (haveNext) {
        size_t g0 = (size_t)(nc4 * 64 + vc0) * 1024 + nkt * 64 + fc0 * 8;
        size_t g1 = (size_t)(nc4 * 64 + vc1) * 1024 + nkt * 64 + fc0 * 8;
        fvh0 = *(const bf8*)&vhg[g0]; fvl0 = *(const bf8*)&vlg[g0];
        fvh1 = *(const bf8*)&vhg[g1]; fvl1 = *(const bf8*)&vlg[g1];
      }
      h8 fkh0, fkh1, fkl0, fkl1;
      if (pfK) {
        size_t g0 = (size_t)((kt + 1) * 64 + vc0) * 64 + fc0 * 8;
        size_t g1 = (size_t)((kt + 1) * 64 + vc1) * 64 + fc0 * 8;
        fkh0 = *(const h8*)&kgh[g0]; fkl0 = *(const h8*)&kgl[g0];
        fkh1 = *(const h8*)&kgh[g1]; fkl1 = *(const h8*)&kgl[g1];
      }

      // PV MFMAs on current buffer
#pragma unroll
      for (int n2 = 0; n2 < 4; n2++) {
        int nt = c4 * 4 + n2;
        int vrow = n2 * 16 + ln;
        bf8 vh0 = *(const bf8*)&VhS[buf][vrow][(quad * 8) ^ swz];
        bf8 vh1 = *(const bf8*)&VhS[buf][vrow][(32 + quad * 8) ^ swz];
        bf8 vl0 = *(const bf8*)&VlS[buf][vrow][(quad * 8) ^ swz];
        bf8 vl1 = *(const bf8*)&VlS[buf][vrow][(32 + quad * 8) ^ swz];
        O[nt] = __builtin_amdgcn_mfma_f32_16x16x32_bf16(ph0, vh0, O[nt], 0, 0, 0);
        O[nt] = __builtin_amdgcn_mfma_f32_16x16x32_bf16(ph1, vh1, O[nt], 0, 0, 0);
        O[nt] = __builtin_amdgcn_mfma_f32_16x16x32_bf16(ph0, vl0, O[nt], 0, 0, 0);
        O[nt] = __builtin_amdgcn_mfma_f32_16x16x32_bf16(ph1, vl1, O[nt], 0, 0, 0);
        O[nt] = __builtin_amdgcn_mfma_f32_16x16x32_bf16(pl0, vh0, O[nt], 0, 0, 0);
        O[nt] = __builtin_amdgcn_mfma_f32_16x16x32_bf16(pl1, vh1, O[nt], 0, 0, 0);
      }

      // write prefetched data into the other buffer / K tile
      if (haveNext) {
        int cc0 = (fc0 * 8) ^ ((vc0 & 7) << 3);
        int cc1 = (fc0 * 8) ^ ((vc1 & 7) << 3);
        *(bf8*)&VhS[buf ^ 1][vc0][cc0] = fvh0;
        *(bf8*)&VlS[buf ^ 1][vc0][cc0] = fvl0;
        *(bf8*)&VhS[buf ^ 1][vc1][cc1] = fvh1;
        *(bf8*)&VlS[buf ^ 1][vc1][cc1] = fvl1;
      }
      if (pfK) {
        int cc0 = (fc0 * 8) ^ ((vc0 & 7) << 3);
        int cc1 = (fc0 * 8) ^ ((vc1 & 7) << 3);
        *(h8*)&KhS[vc0][cc0] = fkh0;
        *(h8*)&KlS[vc0][cc0] = fkl0;
        *(h8*)&KhS[vc1][cc1] = fkh1;
        *(h8*)&KlS[vc1][cc1] = fkl1;
      }
      __syncthreads();   // B3[c4]
    }
  }

  // ---- epilogue (own rows/regs; no barrier needed) ----
#pragma unroll
  for (int r = 0; r < 4; r++) {
    float linv = 1.f / l[r];
    int row = qt * 64 + wv * 16 + quad * 4 + r;
    float* dst = ob + (size_t)h * 1048576 + (size_t)(b * 1024 + row) * 256;
#pragma unroll
    for (int nt = 0; nt < 16; nt++)
      dst[nt * 16 + ln] = O[nt][r] * linv;
  }
}

// ---------------------------------------------------------------------------
// BN stats (R4 verbatim)
// ---------------------------------------------------------------------------
__global__ __launch_bounds__(256) void k_bnstats(
    const float* __restrict__ a, const float* __restrict__ b,
    float* __restrict__ stats, int addB)
{
  const int h = blockIdx.y, r0 = blockIdx.x * 64, c = threadIdx.x;
  const float* pa = a + (size_t)h * 1048576 + r0 * 256 + c;
  float s = 0.f, s2 = 0.f;
  if (addB) {
    const float* pb = b + (size_t)h * 1048576 + r0 * 256 + c;
    for (int r = 0; r < 64; r++) {
      float y = pa[r * 256] + pb[r * 256];
      s += y; s2 += y * y;
    }
  } else {
    for (int r = 0; r < 64; r++) {
      float y = pa[r * 256];
      s += y; s2 += y * y;
    }
  }
  atomicAdd(&stats[(h * 256 + c) * 2], s);
  atomicAdd(&stats[(h * 256 + c) * 2 + 1], s2);
}

// ---------------------------------------------------------------------------
// BN apply (R4 verbatim)
// ---------------------------------------------------------------------------
__global__ __launch_bounds__(256) void k_bnapply(
    const float* __restrict__ a, const float* __restrict__ b,
    const float* __restrict__ stats,
    const float* __restrict__ gamma, const float* __restrict__ beta,
    float* __restrict__ dst, int t, int addB, int transposed)
{
  const int h = blockIdx.y, r0 = blockIdx.x * 64, c = threadIdx.x;
  float s  = stats[(h * 256 + c) * 2];
  float s2 = stats[(h * 256 + c) * 2 + 1];
  float mean = s * (1.f / 4096.f);
  float var  = s2 * (1.f / 4096.f) - mean * mean;
  float inv  = rsqrtf(var + EPSV);
  float g  = gamma[(h * TT + t) * 256 + c] * inv;
  float bt = beta[(h * TT + t) * 256 + c];
  const float* pa = a + (size_t)h * 1048576 + r0 * 256 + c;
  const float* pb = addB ? (b + (size_t)h * 1048576 + r0 * 256 + c) : nullptr;
  for (int r = 0; r < 64; r++) {
    float y = pa[r * 256];
    if (addB) y += pb[r * 256];
    float o = (y - mean) * g + bt;
    int rg = r0 + r;
    if (transposed) dst[((size_t)rg * HH + h) * 256 + c] = o;
    else            dst[(size_t)h * 1048576 + rg * 256 + c] = o;
  }
}

// ---------------------------------------------------------------------------
extern "C" void kernel_launch(void* const* d_in, const int* in_sizes, int n_in,
                              void* d_out, int out_size, void* d_ws, size_t ws_size,
                              hipStream_t stream)
{
  const float* x   = (const float*)d_in[0];
  const float* Win = (const float*)d_in[1];
  const float* Wq  = (const float*)d_in[2];
  const float* Wk  = (const float*)d_in[3];
  const float* Wv  = (const float*)d_in[4];
  const float* Wd  = (const float*)d_in[5];
  const float* g1  = (const float*)d_in[6];
  const float* b1  = (const float*)d_in[7];
  const float* g2  = (const float*)d_in[8];
  const float* b2  = (const float*)d_in[9];
  float* out = (float*)d_out;
  float* ws  = (float*)d_ws;

  float* net   = ws;                       // H*BS*V fp32       =  8,388,608 f
  float* tmp   = net + 8388608;            // H*BS*V fp32       =  8,388,608 f
  float* stats = tmp + 8388608;            // 8 phases * H*V*2  =     32,768 f
  // q/k split-f16 hi/lo, [h*4+b][s][kd] halves
  _Float16* qph = (_Float16*)(stats + 32768);  // 2,097,152 h
  _Float16* qpl = qph + 2097152;               // 2,097,152 h
  _Float16* kph = qpl + 2097152;               // 2,097,152 h
  _Float16* kpl = kph + 2097152;               // 2,097,152 h
  short* vth   = (short*)(kpl + 2097152);  // H*B*V*S bf16 hi   =  8,388,608 s
  short* vtl   = vth + 8388608;            // H*B*V*S bf16 lo   =  8,388,608 s
  _Float16* wph = (_Float16*)(vtl + 8388608);  // prepped weights hi = 1,310,720 h
  _Float16* wpl = wph + 1310720;               // prepped weights lo = 1,310,720 h

  hipMemsetAsync(stats, 0, 8 * HH * VV * 2 * sizeof(float), stream);

  k_in_dense<<<dim3(64, 4), 256, 0, stream>>>(x, Win, net);

  for (int t = 0; t < TT; t++) {
    float* st1 = stats + (t * 2 + 0) * HH * VV * 2;
    float* st2 = stats + (t * 2 + 1) * HH * VV * 2;

    k_prep<<<dim3(10, 4, 8), 256, 0, stream>>>(Wq, Wk, Wv, Wd, wph, wpl, t);
    k_mm_qkv<<<dim3(64, 8), 256, 0, stream>>>(net, wph, wpl, qph, qpl, kph, kpl, vth, vtl);
    k_attn<<<dim3(16, 4, 8), 256, 0, stream>>>(qph, qpl, kph, kpl, vth, vtl, tmp);

    k_bnstats<<<dim3(64, 8), 256, 0, stream>>>(net, tmp, st1, 1);
    k_bnapply<<<dim3(64, 8), 256, 0, stream>>>(net, tmp, st1, g1, b1, net, t, 1, 0);

    k_mm_dense<<<dim3(64, 8), 256, 0, stream>>>(net, wph, wpl, tmp);

    k_bnstats<<<dim3(64, 8), 256, 0, stream>>>(tmp, nullptr, st2, 0);
    if (t < TT - 1)
      k_bnapply<<<dim3(64, 8), 256, 0, stream>>>(tmp, nullptr, st2, g2, b2, net, t, 0, 0);
    else
      k_bnapply<<<dim3(64, 8), 256, 0, stream>>>(tmp, nullptr, st2, g2, b2, out, t, 0, 1);
  }
}

// Round 5
// 903.320 us; speedup vs baseline: 2.1931x; 1.1737x over previous
//
#include <hip/hip_runtime.h>
#include <hip/hip_bf16.h>
#include <math.h>

// Problem constants
#define BB   4
#define SS   1024
#define VV   256
#define KDIM 64
#define HH   8
#define TT   4
#define EPSV 1e-3f
#define SCL  0.125f        // KD^-0.5
#define INV2048 4.8828125e-4f

typedef float f4 __attribute__((ext_vector_type(4)));
typedef short bf8 __attribute__((ext_vector_type(8)));       // 8 bf16
typedef _Float16 h8 __attribute__((ext_vector_type(8)));     // 8 f16
typedef _Float16 h4 __attribute__((ext_vector_type(4)));

#define LDP 68   // fp32 GEMM LDS stride (floats)
#define LHS 68   // split-f16 GEMM LDS stride (halves; 34 dwords -> 2-way, free)

__device__ __forceinline__ short f2bf(float x) {
  __hip_bfloat16 h = __float2bfloat16(x);   // RNE
  return *reinterpret_cast<short*>(&h);
}
__device__ __forceinline__ float bf2f(short h) {
  union { unsigned u; float f; } cv;
  cv.u = ((unsigned)(unsigned short)h) << 16;
  return cv.f;
}

// ---------------------------------------------------------------------------
// identity affine init (t=0 consumers)
// ---------------------------------------------------------------------------
__global__ __launch_bounds__(256) void k_init(float* __restrict__ g, float* __restrict__ b)
{
  int i = blockIdx.x * 256 + threadIdx.x;
  g[i] = 1.f; b[i] = 0.f;
}

// ---------------------------------------------------------------------------
// stats + gamma/beta -> per-column affine (g', b'):  BN(x) = x*g' + b'
// ---------------------------------------------------------------------------
__global__ __launch_bounds__(256) void k_affine(
    const float* __restrict__ st, const float* __restrict__ gamma,
    const float* __restrict__ beta, int t,
    float* __restrict__ ag, float* __restrict__ ab)
{
  int h = blockIdx.x, c = threadIdx.x;
  float s  = st[(h * 256 + c) * 2];
  float s2 = st[(h * 256 + c) * 2 + 1];
  float mean = s * (1.f / 4096.f);
  float var  = s2 * (1.f / 4096.f) - mean * mean;
  float g = gamma[(h * TT + t) * 256 + c] * rsqrtf(var + EPSV);
  ag[h * 256 + c] = g;
  ab[h * 256 + c] = beta[(h * TT + t) * 256 + c] - mean * g;
}

// ---------------------------------------------------------------------------
// fp32 GEMM core (R4, proven) — used only by k_in_dense (1 dispatch).
// ---------------------------------------------------------------------------
__device__ __forceinline__ void gemm_core(
    const float* __restrict__ A, const float* __restrict__ Bm, int ldb,
    float acc[4][4], float (*As)[LDP], float (*Bs)[LDP])
{
  const int tid = threadIdx.x;
  const int tx = tid & 15, ty = tid >> 4;
#pragma unroll
  for (int i = 0; i < 4; i++)
#pragma unroll
    for (int j = 0; j < 4; j++) acc[i][j] = 0.f;

  for (int k0 = 0; k0 < 256; k0 += 16) {
#pragma unroll
    for (int l = 0; l < 4; l++) {
      int e = tid + l * 256;
      int r = e >> 4, kk = e & 15;
      As[kk][r] = A[r * 256 + k0 + kk];
      int rb = e >> 6, nn = e & 63;
      Bs[rb][nn] = Bm[(k0 + rb) * ldb + nn];
    }
    __syncthreads();
#pragma unroll
    for (int kk = 0; kk < 16; kk++) {
      f4 av = *(const f4*)&As[kk][ty * 4];
      f4 bv = *(const f4*)&Bs[kk][tx * 4];
#pragma unroll
      for (int i = 0; i < 4; i++)
#pragma unroll
        for (int j = 0; j < 4; j++)
          acc[i][j] += av[i] * bv[j];
    }
    __syncthreads();
  }
}

// ---------------------------------------------------------------------------
// net0 = x @ W_in, broadcast into all H head slots (R4 verbatim)
// ---------------------------------------------------------------------------
__global__ __launch_bounds__(256) void k_in_dense(
    const float* __restrict__ x, const float* __restrict__ Win,
    float* __restrict__ net)
{
  __shared__ __align__(16) float As[16][LDP];
  __shared__ __align__(16) float Bs[16][LDP];
  const int mt = blockIdx.x, nt = blockIdx.y;
  float acc[4][4];
  gemm_core(x + mt * 64 * 256, Win + nt * 64, 256, acc, As, Bs);
  const int tx = threadIdx.x & 15, ty = threadIdx.x >> 4;
#pragma unroll
  for (int i = 0; i < 4; i++) {
    f4 v;
#pragma unroll
    for (int j = 0; j < 4; j++) v[j] = acc[i][j];
    int row = mt * 64 + ty * 4 + i;
    int col = nt * 64 + tx * 4;
    for (int h = 0; h < HH; h++)
      *(f4*)&net[(size_t)h * 1048576 + row * 256 + col] = v;
  }
}

// ---------------------------------------------------------------------------
// Weight prep (per t): transpose + split into f16 hi/lo, layout [n][k(256)].
// ---------------------------------------------------------------------------
__global__ __launch_bounds__(256) void k_prep(
    const float* __restrict__ Wq, const float* __restrict__ Wk,
    const float* __restrict__ Wv, const float* __restrict__ Wd,
    _Float16* __restrict__ oh, _Float16* __restrict__ ol, int t)
{
  __shared__ __align__(16) _Float16 Th[64][LHS];
  __shared__ __align__(16) _Float16 Tl[64][LHS];
  const int xb = blockIdx.x, kb = blockIdx.y, h = blockIdx.z;
  const int tid = threadIdx.x;
  const float* src; int N, nb; size_t dbase;
  if (xb == 0)      { src = Wq; N = 64;  nb = 0;      dbase = (size_t)h * 16384; }
  else if (xb == 1) { src = Wk; N = 64;  nb = 0;      dbase = 131072 + (size_t)h * 16384; }
  else if (xb < 6)  { src = Wv; N = 256; nb = xb - 2; dbase = 262144 + (size_t)h * 65536; }
  else              { src = Wd; N = 256; nb = xb - 6; dbase = 786432 + (size_t)h * 65536; }
  src += (size_t)(h * TT + t) * 256 * N;
#pragma unroll
  for (int i = 0; i < 4; i++) {
    int fi = tid + i * 256;
    int r = fi >> 4, c4 = fi & 15;
    f4 w = *(const f4*)&src[(size_t)(kb * 64 + r) * N + nb * 64 + c4 * 4];
    h4 hv, lv;
#pragma unroll
    for (int j = 0; j < 4; j++) {
      _Float16 hi = (_Float16)w[j];
      hv[j] = hi;
      lv[j] = (_Float16)((w[j] - (float)hi) * 2048.f);
    }
    *(h4*)&Th[r][c4 * 4] = hv;
    *(h4*)&Tl[r][c4 * 4] = lv;
  }
  __syncthreads();
#pragma unroll
  for (int i = 0; i < 4; i++) {
    int fo = tid + i * 256;
    int nr = fo >> 4, k4 = fo & 15;
    h4 hv, lv;
#pragma unroll
    for (int j = 0; j < 4; j++) { hv[j] = Th[k4 * 4 + j][nr]; lv[j] = Tl[k4 * 4 + j][nr]; }
    size_t d = dbase + (size_t)(nb * 64 + nr) * 256 + kb * 64 + k4 * 4;
    *(h4*)&oh[d] = hv;
    *(h4*)&ol[d] = lv;
  }
}

// ---------------------------------------------------------------------------
// A-tile staging with on-the-fly per-column affine (BN fold):
// issue loads to regs (+fma), split+write to LDS later.
// ---------------------------------------------------------------------------
__device__ __forceinline__ void stage_issue_aff(
    const float* __restrict__ A, const float* __restrict__ ag,
    const float* __restrict__ ab, int kc, int tid, f4 w[4])
{
#pragma unroll
  for (int i = 0; i < 4; i++) {
    int fi = tid + i * 256;
    int r = fi >> 4, c4 = fi & 15;
    f4 raw = *(const f4*)&A[(size_t)r * 256 + kc * 64 + c4 * 4];
    f4 g = *(const f4*)&ag[kc * 64 + c4 * 4];
    f4 b = *(const f4*)&ab[kc * 64 + c4 * 4];
#pragma unroll
    for (int j = 0; j < 4; j++) w[i][j] = fmaf(raw[j], g[j], b[j]);
  }
}
__device__ __forceinline__ void stage_write(
    const f4 w[4], int tid, _Float16 (*Ah)[LHS], _Float16 (*Al)[LHS])
{
#pragma unroll
  for (int i = 0; i < 4; i++) {
    int fi = tid + i * 256;
    int r = fi >> 4, c4 = fi & 15;
    h4 hv, lv;
#pragma unroll
    for (int j = 0; j < 4; j++) {
      _Float16 hi = (_Float16)w[i][j];
      hv[j] = hi;
      lv[j] = (_Float16)((w[i][j] - (float)hi) * 2048.f);
    }
    *(h4*)&Ah[r][c4 * 4] = hv;
    *(h4*)&Al[r][c4 * 4] = lv;
  }
}

// ---------------------------------------------------------------------------
// QKV GEMM (merged): A = affine(net) staged once per half, dbuf + prefetch.
// grid (64 mt, 8 h).
// ---------------------------------------------------------------------------
__global__ __launch_bounds__(256) void k_mm_qkv(
    const float* __restrict__ net,
    const float* __restrict__ affg, const float* __restrict__ affb,
    const _Float16* __restrict__ wph, const _Float16* __restrict__ wpl,
    _Float16* __restrict__ qph, _Float16* __restrict__ qpl,
    _Float16* __restrict__ kph, _Float16* __restrict__ kpl,
    short* __restrict__ vth, short* __restrict__ vtl)
{
  __shared__ __align__(16) _Float16 Ah[2][64][LHS];
  __shared__ __align__(16) _Float16 Al[2][64][LHS];
  const int mt = blockIdx.x, h = blockIdx.y;
  const int tid = threadIdx.x, wv = tid >> 6, lane = tid & 63;
  const int ln = lane & 15, quad = lane >> 4;
  const float* A = net + (size_t)h * 1048576 + (size_t)mt * 64 * 256;
  const float* ag = affg + h * 256;
  const float* ab = affb + h * 256;

  for (int half = 0; half < 2; half++) {
    size_t bb[3];
#pragma unroll
    for (int j = 0; j < 3; j++) {
      int nt = half * 3 + j;
      if (nt == 0)      bb[j] = (size_t)h * 16384;
      else if (nt == 1) bb[j] = 131072 + (size_t)h * 16384;
      else              bb[j] = 262144 + (size_t)h * 65536 + (size_t)(nt - 2) * 16384;
      bb[j] += (size_t)(wv * 16 + ln) * 256;
    }

    f4 mn[3][4], cr[3][4];
#pragma unroll
    for (int j = 0; j < 3; j++)
#pragma unroll
      for (int mf = 0; mf < 4; mf++) {
        mn[j][mf] = (f4){0.f, 0.f, 0.f, 0.f};
        cr[j][mf] = (f4){0.f, 0.f, 0.f, 0.f};
      }

    f4 w[4];
    stage_issue_aff(A, ag, ab, 0, tid, w);
    stage_write(w, tid, Ah[0], Al[0]);
    __syncthreads();

    for (int kc = 0; kc < 4; kc++) {
      const int buf = kc & 1;
      if (kc < 3) stage_issue_aff(A, ag, ab, kc + 1, tid, w);
#pragma unroll
      for (int j = 0; j < 3; j++) {
        const _Float16* bh = wph + bb[j] + kc * 64;
        const _Float16* bl = wpl + bb[j] + kc * 64;
        h8 bh0 = *(const h8*)&bh[quad * 8];
        h8 bh1 = *(const h8*)&bh[32 + quad * 8];
        h8 bl0 = *(const h8*)&bl[quad * 8];
        h8 bl1 = *(const h8*)&bl[32 + quad * 8];
#pragma unroll
        for (int mf = 0; mf < 4; mf++) {
          h8 ah0 = *(const h8*)&Ah[buf][mf * 16 + ln][quad * 8];
          h8 ah1 = *(const h8*)&Ah[buf][mf * 16 + ln][32 + quad * 8];
          h8 al0 = *(const h8*)&Al[buf][mf * 16 + ln][quad * 8];
          h8 al1 = *(const h8*)&Al[buf][mf * 16 + ln][32 + quad * 8];
          mn[j][mf] = __builtin_amdgcn_mfma_f32_16x16x32_f16(ah0, bh0, mn[j][mf], 0, 0, 0);
          mn[j][mf] = __builtin_amdgcn_mfma_f32_16x16x32_f16(ah1, bh1, mn[j][mf], 0, 0, 0);
          cr[j][mf] = __builtin_amdgcn_mfma_f32_16x16x32_f16(ah0, bl0, cr[j][mf], 0, 0, 0);
          cr[j][mf] = __builtin_amdgcn_mfma_f32_16x16x32_f16(ah1, bl1, cr[j][mf], 0, 0, 0);
          cr[j][mf] = __builtin_amdgcn_mfma_f32_16x16x32_f16(al0, bh0, cr[j][mf], 0, 0, 0);
          cr[j][mf] = __builtin_amdgcn_mfma_f32_16x16x32_f16(al1, bh1, cr[j][mf], 0, 0, 0);
        }
      }
      if (kc < 3) stage_write(w, tid, Ah[buf ^ 1], Al[buf ^ 1]);
      __syncthreads();
    }

#pragma unroll
    for (int j = 0; j < 3; j++) {
      int nt = half * 3 + j;
      if (nt <= 1) {
        _Float16* dh = (nt == 0) ? qph : kph;
        _Float16* dl = (nt == 0) ? qpl : kpl;
        int col = wv * 16 + ln;
#pragma unroll
        for (int mf = 0; mf < 4; mf++)
#pragma unroll
          for (int r = 0; r < 4; r++) {
            int row = mt * 64 + mf * 16 + quad * 4 + r;
            int b_ = row >> 10, sI = row & 1023;
            float v = mn[j][mf][r] + cr[j][mf][r] * INV2048;
            _Float16 hi = (_Float16)v;
            size_t idx = ((size_t)(h * 4 + b_) * 1024 + sI) * 64 + col;
            dh[idx] = hi;
            dl[idx] = (_Float16)((v - (float)hi) * 2048.f);
          }
      } else {
        int c = (nt - 2) * 64 + wv * 16 + ln;
#pragma unroll
        for (int mf = 0; mf < 4; mf++)
#pragma unroll
          for (int r = 0; r < 4; r++) {
            int row = mt * 64 + mf * 16 + quad * 4 + r;
            int b_ = row >> 10, sI = row & 1023;
            float v = mn[j][mf][r] + cr[j][mf][r] * INV2048;
            short hi = f2bf(v);
            size_t idx = ((size_t)(h * 4 + b_) * 256 + c) * 1024 + sI;
            vth[idx] = hi;
            vtl[idx] = f2bf(v - bf2f(hi));
          }
      }
    }
  }
}

// ---------------------------------------------------------------------------
// Dense GEMM (merged) + fused BN1-apply + residual + BN2-stats:
// A = affine1(buf1); epilogue y2 = affine1(buf1) + relu(mm) -> buf2, stats2.
// grid (64 mt, 8 h).
// ---------------------------------------------------------------------------
__global__ __launch_bounds__(256) void k_mm_dense(
    const float* __restrict__ buf1,
    const float* __restrict__ affg, const float* __restrict__ affb,
    const _Float16* __restrict__ wph, const _Float16* __restrict__ wpl,
    float* __restrict__ buf2, float* __restrict__ st)
{
  __shared__ __align__(16) _Float16 Ah[2][64][LHS];
  __shared__ __align__(16) _Float16 Al[2][64][LHS];
  const int mt = blockIdx.x, h = blockIdx.y;
  const int tid = threadIdx.x, wv = tid >> 6, lane = tid & 63;
  const int ln = lane & 15, quad = lane >> 4;
  const float* a1 = buf1 + (size_t)h * 1048576;
  float* o2 = buf2 + (size_t)h * 1048576;
  const float* A = a1 + (size_t)mt * 64 * 256;
  const float* ag = affg + h * 256;
  const float* ab = affb + h * 256;

  for (int half = 0; half < 2; half++) {
    size_t bb[2];
#pragma unroll
    for (int j = 0; j < 2; j++) {
      int nt = half * 2 + j;
      bb[j] = 786432 + (size_t)h * 65536 + (size_t)nt * 16384
            + (size_t)(wv * 16 + ln) * 256;
    }

    f4 mn[2][4], cr[2][4];
#pragma unroll
    for (int j = 0; j < 2; j++)
#pragma unroll
      for (int mf = 0; mf < 4; mf++) {
        mn[j][mf] = (f4){0.f, 0.f, 0.f, 0.f};
        cr[j][mf] = (f4){0.f, 0.f, 0.f, 0.f};
      }

    f4 w[4];
    stage_issue_aff(A, ag, ab, 0, tid, w);
    stage_write(w, tid, Ah[0], Al[0]);
    __syncthreads();

    for (int kc = 0; kc < 4; kc++) {
      const int buf = kc & 1;
      if (kc < 3) stage_issue_aff(A, ag, ab, kc + 1, tid, w);
#pragma unroll
      for (int j = 0; j < 2; j++) {
        const _Float16* bh = wph + bb[j] + kc * 64;
        const _Float16* bl = wpl + bb[j] + kc * 64;
        h8 bh0 = *(const h8*)&bh[quad * 8];
        h8 bh1 = *(const h8*)&bh[32 + quad * 8];
        h8 bl0 = *(const h8*)&bl[quad * 8];
        h8 bl1 = *(const h8*)&bl[32 + quad * 8];
#pragma unroll
        for (int mf = 0; mf < 4; mf++) {
          h8 ah0 = *(const h8*)&Ah[buf][mf * 16 + ln][quad * 8];
          h8 ah1 = *(const h8*)&Ah[buf][mf * 16 + ln][32 + quad * 8];
          h8 al0 = *(const h8*)&Al[buf][mf * 16 + ln][quad * 8];
          h8 al1 = *(const h8*)&Al[buf][mf * 16 + ln][32 + quad * 8];
          mn[j][mf] = __builtin_amdgcn_mfma_f32_16x16x32_f16(ah0, bh0, mn[j][mf], 0, 0, 0);
          mn[j][mf] = __builtin_amdgcn_mfma_f32_16x16x32_f16(ah1, bh1, mn[j][mf], 0, 0, 0);
          cr[j][mf] = __builtin_amdgcn_mfma_f32_16x16x32_f16(ah0, bl0, cr[j][mf], 0, 0, 0);
          cr[j][mf] = __builtin_amdgcn_mfma_f32_16x16x32_f16(ah1, bl1, cr[j][mf], 0, 0, 0);
          cr[j][mf] = __builtin_amdgcn_mfma_f32_16x16x32_f16(al0, bh0, cr[j][mf], 0, 0, 0);
          cr[j][mf] = __builtin_amdgcn_mfma_f32_16x16x32_f16(al1, bh1, cr[j][mf], 0, 0, 0);
        }
      }
      if (kc < 3) stage_write(w, tid, Ah[buf ^ 1], Al[buf ^ 1]);
      __syncthreads();
    }

#pragma unroll
    for (int j = 0; j < 2; j++) {
      int nt = half * 2 + j;
      int col = nt * 64 + wv * 16 + ln;
      float gc = ag[col], bc = ab[col];
      float s1 = 0.f, s2 = 0.f;
#pragma unroll
      for (int mf = 0; mf < 4; mf++)
#pragma unroll
        for (int r = 0; r < 4; r++) {
          int row = mt * 64 + mf * 16 + quad * 4 + r;
          size_t idx = (size_t)row * 256 + col;
          float v = mn[j][mf][r] + cr[j][mf][r] * INV2048;
          float yv = fmaf(a1[idx], gc, bc) + fmaxf(v, 0.f);
          o2[idx] = yv;
          s1 += yv; s2 += yv * yv;
        }
      s1 += __shfl_xor(s1, 16, 64); s1 += __shfl_xor(s1, 32, 64);
      s2 += __shfl_xor(s2, 16, 64); s2 += __shfl_xor(s2, 32, 64);
      if (quad == 0) {
        atomicAdd(&st[(h * 256 + col) * 2],     s1);
        atomicAdd(&st[(h * 256 + col) * 2 + 1], s2);
      }
    }
  }
}

// ---------------------------------------------------------------------------
// Flash attention (v4 core) + T13 defer-max + fused residual/BN1-stats
// epilogue: y1 = affine(net) + O/l -> buf1, stats1 atomics.
// grid (16 q-tiles, 4 batch, 8 heads)
// ---------------------------------------------------------------------------
__global__ __launch_bounds__(256, 2) void k_attn(
    const _Float16* __restrict__ qfh, const _Float16* __restrict__ qfl,
    const _Float16* __restrict__ kfh, const _Float16* __restrict__ kfl,
    const short* __restrict__ vth, const short* __restrict__ vtl,
    const float* __restrict__ resid,
    const float* __restrict__ affg, const float* __restrict__ affb,
    float* __restrict__ st, float* __restrict__ obuf)
{
  __shared__ __align__(16) short KhS[64][64];     // 8 KB
  __shared__ __align__(16) short KlS[64][64];     // 8 KB
  __shared__ __align__(16) short PhS[64][64];     // 8 KB
  __shared__ __align__(16) short PlS[64][64];     // 8 KB
  __shared__ __align__(16) short VhS[2][64][64];  // 16 KB
  __shared__ __align__(16) short VlS[2][64][64];  // 16 KB  => 64 KB total

  const int qt = blockIdx.x, b = blockIdx.y, h = blockIdx.z;
  const int tid = threadIdx.x;
  const int wv = tid >> 6, lane = tid & 63, ln = lane & 15, quad = lane >> 4;
  const int hb = h * 4 + b;
  const int swz = (ln & 7) << 3;

  const _Float16* qgh = qfh + ((size_t)hb * 1024 + qt * 64 + wv * 16 + ln) * 64;
  const _Float16* qgl = qfl + ((size_t)hb * 1024 + qt * 64 + wv * 16 + ln) * 64;
  h8 aqh0 = *(const h8*)&qgh[quad * 8];
  h8 aqh1 = *(const h8*)&qgh[32 + quad * 8];
  h8 aql0 = *(const h8*)&qgl[quad * 8];
  h8 aql1 = *(const h8*)&qgl[32 + quad * 8];

  const _Float16* kgh = kfh + (size_t)hb * 65536;   // [1024 s][64 kd]
  const _Float16* kgl = kfl + (size_t)hb * 65536;
  const short* vhg = vth + (size_t)hb * 262144;     // [256 vcol][1024 s]
  const short* vlg = vtl + (size_t)hb * 262144;

  float m[4] = {-1e30f, -1e30f, -1e30f, -1e30f};
  float l[4] = {0.f, 0.f, 0.f, 0.f};
  f4 O[16];
#pragma unroll
  for (int nt = 0; nt < 16; nt++) O[nt] = (f4){0.f, 0.f, 0.f, 0.f};

  // ---- prologue: stage K(0) and V(kt=0, c4=0) into buf 0 ----
#pragma unroll
  for (int i = 0; i < 2; i++) {
    int e = tid + i * 256;
    int r = e >> 3, c8 = e & 7;
    int cc = (c8 * 8) ^ ((r & 7) << 3);
    *(h8*)&KhS[r][cc] = *(const h8*)&kgh[(size_t)r * 64 + c8 * 8];
    *(h8*)&KlS[r][cc] = *(const h8*)&kgl[(size_t)r * 64 + c8 * 8];
  }
#pragma unroll
  for (int i = 0; i < 2; i++) {
    int e = tid + i * 256;
    int vc = e >> 3, fc = e & 7;
    int cc = (fc * 8) ^ ((vc & 7) << 3);
    size_t g = (size_t)vc * 1024 + fc * 8;
    *(bf8*)&VhS[0][vc][cc] = *(const bf8*)&vhg[g];
    *(bf8*)&VlS[0][vc][cc] = *(const bf8*)&vlg[g];
  }
  __syncthreads();

  for (int kt = 0; kt < 16; kt++) {
    // ---- QK^T ----
    f4 sv[4];
#pragma unroll
    for (int nf = 0; nf < 4; nf++) {
      int row = nf * 16 + ln;
      h8 bkh0 = *(const h8*)&KhS[row][(quad * 8) ^ swz];
      h8 bkh1 = *(const h8*)&KhS[row][(32 + quad * 8) ^ swz];
      h8 bkl0 = *(const h8*)&KlS[row][(quad * 8) ^ swz];
      h8 bkl1 = *(const h8*)&KlS[row][(32 + quad * 8) ^ swz];
      f4 mn = (f4){0.f, 0.f, 0.f, 0.f};
      f4 cr = (f4){0.f, 0.f, 0.f, 0.f};
      mn = __builtin_amdgcn_mfma_f32_16x16x32_f16(aqh0, bkh0, mn, 0, 0, 0);
      mn = __builtin_amdgcn_mfma_f32_16x16x32_f16(aqh1, bkh1, mn, 0, 0, 0);
      cr = __builtin_amdgcn_mfma_f32_16x16x32_f16(aqh0, bkl0, cr, 0, 0, 0);
      cr = __builtin_amdgcn_mfma_f32_16x16x32_f16(aqh1, bkl1, cr, 0, 0, 0);
      cr = __builtin_amdgcn_mfma_f32_16x16x32_f16(aql0, bkh0, cr, 0, 0, 0);
      cr = __builtin_amdgcn_mfma_f32_16x16x32_f16(aql1, bkh1, cr, 0, 0, 0);
#pragma unroll
      for (int r = 0; r < 4; r++) sv[nf][r] = (mn[r] + cr[r] * INV2048) * SCL;
    }

    // ---- online softmax with defer-max (T13, THR=8) ----
    float mloc[4];
#pragma unroll
    for (int r = 0; r < 4; r++) {
      float v0 = fmaxf(fmaxf(sv[0][r], sv[1][r]), fmaxf(sv[2][r], sv[3][r]));
#pragma unroll
      for (int d = 1; d < 16; d <<= 1)
        v0 = fmaxf(v0, __shfl_xor(v0, d, 64));
      mloc[r] = v0;
    }
    float growth = fmaxf(fmaxf(mloc[0] - m[0], mloc[1] - m[1]),
                         fmaxf(mloc[2] - m[2], mloc[3] - m[3]));
    if (__any(growth > 8.f)) {
      float alpha[4];
#pragma unroll
      for (int r = 0; r < 4; r++) {
        float mnew = fmaxf(m[r], mloc[r]);
        alpha[r] = __expf(m[r] - mnew);
        m[r] = mnew;
        l[r] *= alpha[r];
      }
#pragma unroll
      for (int nt = 0; nt < 16; nt++)
#pragma unroll
        for (int i = 0; i < 4; i++) O[nt][i] *= alpha[i];
    }
#pragma unroll
    for (int r = 0; r < 4; r++) {
      float ls = 0.f;
#pragma unroll
      for (int nf = 0; nf < 4; nf++) {
        float p = __expf(sv[nf][r] - m[r]);
        sv[nf][r] = p;
        ls += p;
      }
#pragma unroll
      for (int d = 1; d < 16; d <<= 1) ls += __shfl_xor(ls, d, 64);
      l[r] += ls;
    }

    // ---- publish P (swizzled; own rows) ----
#pragma unroll
    for (int nf = 0; nf < 4; nf++)
#pragma unroll
      for (int r = 0; r < 4; r++) {
        int row = wv * 16 + quad * 4 + r;
        int c = (nf * 16 + ln) ^ ((row & 7) << 3);
        float p = sv[nf][r];
        short hi = f2bf(p);
        PhS[row][c] = hi;
        PlS[row][c] = f2bf(p - bf2f(hi));
      }
    __syncthreads();   // P ready

    bf8 ph0 = *(const bf8*)&PhS[wv * 16 + ln][(quad * 8) ^ swz];
    bf8 ph1 = *(const bf8*)&PhS[wv * 16 + ln][(32 + quad * 8) ^ swz];
    bf8 pl0 = *(const bf8*)&PlS[wv * 16 + ln][(quad * 8) ^ swz];
    bf8 pl1 = *(const bf8*)&PlS[wv * 16 + ln][(32 + quad * 8) ^ swz];

    for (int c4 = 0; c4 < 4; c4++) {
      const int buf = c4 & 1;
      const bool haveNext = (c4 < 3) || (kt < 15);
      const int nkt = (c4 < 3) ? kt : kt + 1;
      const int nc4 = (c4 < 3) ? c4 + 1 : 0;
      const bool pfK = (c4 == 3) && (kt < 15);

      const int vc0 = tid >> 3, fc0 = tid & 7;
      const int vc1 = vc0 + 32;
      bf8 fvh0, fvh1, fvl0, fvl1;
      if (haveNext) {
        size_t g0 = (size_t)(nc4 * 64 + vc0) * 1024 + nkt * 64 + fc0 * 8;
        size_t g1 = (size_t)(nc4 * 64 + vc1) * 1024 + nkt * 64 + fc0 * 8;
        fvh0 = *(const bf8*)&vhg[g0]; fvl0 = *(const bf8*)&vlg[g0];
        fvh1 = *(const bf8*)&vhg[g1]; fvl1 = *(const bf8*)&vlg[g1];
      }
      h8 fkh0, fkh1, fkl0, fkl1;
      if (pfK) {
        size_t g0 = (size_t)((kt + 1) * 64 + vc0) * 64 + fc0 * 8;
        size_t g1 = (size_t)((kt + 1) * 64 + vc1) * 64 + fc0 * 8;
        fkh0 = *(const h8*)&kgh[g0]; fkl0 = *(const h8*)&kgl[g0];
        fkh1 = *(const h8*)&kgh[g1]; fkl1 = *(const h8*)&kgl[g1];
      }

#pragma unroll
      for (int n2 = 0; n2 < 4; n2++) {
        int nt = c4 * 4 + n2;
        int vrow = n2 * 16 + ln;
        bf8 vh0 = *(const bf8*)&VhS[buf][vrow][(quad * 8) ^ swz];
        bf8 vh1 = *(const bf8*)&VhS[buf][vrow][(32 + quad * 8) ^ swz];
        bf8 vl0 = *(const bf8*)&VlS[buf][vrow][(quad * 8) ^ swz];
        bf8 vl1 = *(const bf8*)&VlS[buf][vrow][(32 + quad * 8) ^ swz];
        O[nt] = __builtin_amdgcn_mfma_f32_16x16x32_bf16(ph0, vh0, O[nt], 0, 0, 0);
        O[nt] = __builtin_amdgcn_mfma_f32_16x16x32_bf16(ph1, vh1, O[nt], 0, 0, 0);
        O[nt] = __builtin_amdgcn_mfma_f32_16x16x32_bf16(ph0, vl0, O[nt], 0, 0, 0);
        O[nt] = __builtin_amdgcn_mfma_f32_16x16x32_bf16(ph1, vl1, O[nt], 0, 0, 0);
        O[nt] = __builtin_amdgcn_mfma_f32_16x16x32_bf16(pl0, vh0, O[nt], 0, 0, 0);
        O[nt] = __builtin_amdgcn_mfma_f32_16x16x32_bf16(pl1, vh1, O[nt], 0, 0, 0);
      }

      if (haveNext) {
        int cc0 = (fc0 * 8) ^ ((vc0 & 7) << 3);
        int cc1 = (fc0 * 8) ^ ((vc1 & 7) << 3);
        *(bf8*)&VhS[buf ^ 1][vc0][cc0] = fvh0;
        *(bf8*)&VlS[buf ^ 1][vc0][cc0] = fvl0;
        *(bf8*)&VhS[buf ^ 1][vc1][cc1] = fvh1;
        *(bf8*)&VlS[buf ^ 1][vc1][cc1] = fvl1;
      }
      if (pfK) {
        int cc0 = (fc0 * 8) ^ ((vc0 & 7) << 3);
        int cc1 = (fc0 * 8) ^ ((vc1 & 7) << 3);
        *(h8*)&KhS[vc0][cc0] = fkh0;
        *(h8*)&KlS[vc0][cc0] = fkl0;
        *(h8*)&KhS[vc1][cc1] = fkh1;
        *(h8*)&KlS[vc1][cc1] = fkl1;
      }
      __syncthreads();
    }
  }

  // ---- fused epilogue: y1 = affine(resid) + O/l -> buf1; BN1 stats ----
  const float* rg = affg + h * 256;
  const float* rb = affb + h * 256;
  const float* rs = resid + (size_t)h * 1048576
                  + (size_t)(b * 1024 + qt * 64 + wv * 16 + quad * 4) * 256;
  float* ds = obuf + (size_t)h * 1048576
            + (size_t)(b * 1024 + qt * 64 + wv * 16 + quad * 4) * 256;
  float linv[4];
#pragma unroll
  for (int r = 0; r < 4; r++) linv[r] = 1.f / l[r];

  float* S1 = (float*)&KhS[0][0];   // 4 KB of the free K tile
  float* S2 = (float*)&KlS[0][0];
#pragma unroll
  for (int nt = 0; nt < 16; nt++) {
    int c = nt * 16 + ln;
    float gc = rg[c], bc = rb[c];
    float s1 = 0.f, s2 = 0.f;
#pragma unroll
    for (int r = 0; r < 4; r++) {
      float yv = fmaf(rs[r * 256 + c], gc, bc) + O[nt][r] * linv[r];
      ds[r * 256 + c] = yv;
      s1 += yv; s2 += yv * yv;
    }
    s1 += __shfl_xor(s1, 16, 64); s1 += __shfl_xor(s1, 32, 64);
    s2 += __shfl_xor(s2, 16, 64); s2 += __shfl_xor(s2, 32, 64);
    if (quad == 0) { S1[wv * 256 + c] = s1; S2[wv * 256 + c] = s2; }
  }
  __syncthreads();
  if (tid < 256) {
    float a1 = S1[tid] + S1[256 + tid] + S1[512 + tid] + S1[768 + tid];
    float a2 = S2[tid] + S2[256 + tid] + S2[512 + tid] + S2[768 + tid];
    atomicAdd(&st[(h * 256 + tid) * 2],     a1);
    atomicAdd(&st[(h * 256 + tid) * 2 + 1], a2);
  }
}

// ---------------------------------------------------------------------------
// BN apply (final t only: transposed output)
// ---------------------------------------------------------------------------
__global__ __launch_bounds__(256) void k_bnapply(
    const float* __restrict__ a, const float* __restrict__ b,
    const float* __restrict__ stats,
    const float* __restrict__ gamma, const float* __restrict__ beta,
    float* __restrict__ dst, int t, int addB, int transposed)
{
  const int h = blockIdx.y, r0 = blockIdx.x * 64, c = threadIdx.x;
  float s  = stats[(h * 256 + c) * 2];
  float s2 = stats[(h * 256 + c) * 2 + 1];
  float mean = s * (1.f / 4096.f);
  float var  = s2 * (1.f / 4096.f) - mean * mean;
  float inv  = rsqrtf(var + EPSV);
  float g  = gamma[(h * TT + t) * 256 + c] * inv;
  float bt = beta[(h * TT + t) * 256 + c];
  const float* pa = a + (size_t)h * 1048576 + r0 * 256 + c;
  const float* pb = addB ? (b + (size_t)h * 1048576 + r0 * 256 + c) : nullptr;
  for (int r = 0; r < 64; r++) {
    float y = pa[r * 256];
    if (addB) y += pb[r * 256];
    float o = (y - mean) * g + bt;
    int rg = r0 + r;
    if (transposed) dst[((size_t)rg * HH + h) * 256 + c] = o;
    else            dst[(size_t)h * 1048576 + rg * 256 + c] = o;
  }
}

// ---------------------------------------------------------------------------
extern "C" void kernel_launch(void* const* d_in, const int* in_sizes, int n_in,
                              void* d_out, int out_size, void* d_ws, size_t ws_size,
                              hipStream_t stream)
{
  const float* x   = (const float*)d_in[0];
  const float* Win = (const float*)d_in[1];
  const float* Wq  = (const float*)d_in[2];
  const float* Wk  = (const float*)d_in[3];
  const float* Wv  = (const float*)d_in[4];
  const float* Wd  = (const float*)d_in[5];
  const float* g1  = (const float*)d_in[6];
  const float* b1  = (const float*)d_in[7];
  const float* g2  = (const float*)d_in[8];
  const float* b2  = (const float*)d_in[9];
  float* out = (float*)d_out;
  float* ws  = (float*)d_ws;

  float* net   = ws;                       // buf2: pre-BN2 state (or net0)
  float* tmp   = net + 8388608;            // buf1: pre-BN1 state (y1)
  float* stats = tmp + 8388608;            // 2 phases * H*V*2 = 8192 f
  float* affg1 = stats + 8192;             // 2048 f each
  float* affb1 = affg1 + 2048;
  float* affg2 = affb1 + 2048;
  float* affb2 = affg2 + 2048;
  float* affgI = affb2 + 2048;
  float* affbI = affgI + 2048;             // ends at stats+20480 < stats+32768
  _Float16* qph = (_Float16*)(stats + 32768);  // 2,097,152 h
  _Float16* qpl = qph + 2097152;
  _Float16* kph = qpl + 2097152;
  _Float16* kpl = kph + 2097152;
  short* vth   = (short*)(kpl + 2097152);
  short* vtl   = vth + 8388608;
  _Float16* wph = (_Float16*)(vtl + 8388608);
  _Float16* wpl = wph + 1310720;

  k_init<<<dim3(8), 256, 0, stream>>>(affgI, affbI);
  k_in_dense<<<dim3(64, 4), 256, 0, stream>>>(x, Win, net);

  for (int t = 0; t < TT; t++) {
    float* st1 = stats;
    float* st2 = stats + 4096;
    hipMemsetAsync(stats, 0, 8192 * sizeof(float), stream);

    const float* cg = (t == 0) ? affgI : affg2;
    const float* cb = (t == 0) ? affbI : affb2;

    k_prep<<<dim3(10, 4, 8), 256, 0, stream>>>(Wq, Wk, Wv, Wd, wph, wpl, t);
    k_mm_qkv<<<dim3(64, 8), 256, 0, stream>>>(net, cg, cb, wph, wpl,
                                              qph, qpl, kph, kpl, vth, vtl);
    k_attn<<<dim3(16, 4, 8), 256, 0, stream>>>(qph, qpl, kph, kpl, vth, vtl,
                                               net, cg, cb, st1, tmp);
    k_affine<<<dim3(8), 256, 0, stream>>>(st1, g1, b1, t, affg1, affb1);
    k_mm_dense<<<dim3(64, 8), 256, 0, stream>>>(tmp, affg1, affb1, wph, wpl,
                                                net, st2);
    if (t < TT - 1)
      k_affine<<<dim3(8), 256, 0, stream>>>(st2, g2, b2, t, affg2, affb2);
    else
      k_bnapply<<<dim3(64, 8), 256, 0, stream>>>(net, nullptr, st2, g2, b2,
                                                 out, t, 0, 1);
  }
}